// Round 1
// baseline (163240.491 us; speedup 1.0000x reference)
//
#include <hip/hip_runtime.h>
#include <cstdint>

// Persistent-kernel fp32 baseline for 3-layer autoregressive LSTM.
// B=64, T=512, F=132, H=1024. Grid = 256 blocks (1/CU), 512 threads (8 waves).
// Each block owns j-columns [4*bid, 4*bid+4) of each of the 3 cells.
// Thread map: b = tid&63 (batch), g = (tid>>6)&3 (gate i/f/g/o), s = tid>>8 (K-half interleave).
// Two grid barriers per step (A: states ready; B: decoder out ready), the second
// skipped when the next step is teacher-forced (doesn't read prev_out).

#define NBLK 256
#define NTHR 512
#define Bn 64
#define Tn 512
#define Fn 132
#define Hn 1024
#define BH (Bn * Hn) // 65536

__device__ __forceinline__ float sigf(float x) { return 1.0f / (1.0f + expf(-x)); }

// Device-scope grid barrier: monotonically increasing counter, target = NBLK*epoch.
__device__ __forceinline__ void gsync(unsigned* bar, unsigned target) {
    __syncthreads();
    if (threadIdx.x == 0) {
        __threadfence(); // make prior global writes visible device-wide
        __hip_atomic_fetch_add(bar, 1u, __ATOMIC_ACQ_REL, __HIP_MEMORY_SCOPE_AGENT);
        while (__hip_atomic_load(bar, __ATOMIC_ACQUIRE, __HIP_MEMORY_SCOPE_AGENT) < target) {
            __builtin_amdgcn_s_sleep(2);
        }
        __threadfence(); // acquire: invalidate stale cached lines for the CU
    }
    __syncthreads();
}

// Stage [64 x kt=132] activation tile transposed into LDS (sact[k][b], stride 65),
// then accumulate one consumer weight set (Wih1, ld=Fn) into accA[0..3].
__device__ __forceinline__ void do_xsrc(const float* __restrict__ src, int ld,
                                        const float* __restrict__ wa,
                                        float* __restrict__ accA,
                                        float* __restrict__ sact, int tid, int b, int s) {
    __syncthreads();
#pragma unroll
    for (int it = 0; it < 5; ++it) {
        const int idx = it * 2048 + (tid << 2);
        if (idx < Bn * Fn) {
            const int bb = idx / Fn;
            const int kk = idx - bb * Fn; // multiple of 4 since Fn%4==0
            const float4 v = *(const float4*)(src + (size_t)bb * ld + kk);
            sact[(kk + 0) * 65 + bb] = v.x;
            sact[(kk + 1) * 65 + bb] = v.y;
            sact[(kk + 2) * 65 + bb] = v.z;
            sact[(kk + 3) * 65 + bb] = v.w;
        }
    }
    __syncthreads();
#pragma unroll 2
    for (int ch = s; ch < Fn / 4; ch += 2) {
        const int k = ch << 2;
        const float a0 = sact[(k + 0) * 65 + b], a1 = sact[(k + 1) * 65 + b];
        const float a2 = sact[(k + 2) * 65 + b], a3 = sact[(k + 3) * 65 + b];
#pragma unroll
        for (int jj = 0; jj < 4; ++jj) {
            const float4 w = *(const float4*)(wa + jj * Fn + k);
            accA[jj] = fmaf(w.x, a0, fmaf(w.y, a1, fmaf(w.z, a2, fmaf(w.w, a3, accA[jj]))));
        }
    }
}

// H-type source (K=1024, 8 tiles of 128), one or two consumer weight sets (ld=Hn).
template <bool HASB>
__device__ __forceinline__ void do_hsrc(const float* __restrict__ src,
                                        const float* __restrict__ wa,
                                        const float* __restrict__ wb,
                                        float* __restrict__ accA, float* __restrict__ accB,
                                        float* __restrict__ sact, int tid, int b, int s) {
    for (int k0 = 0; k0 < Hn; k0 += 128) {
        __syncthreads();
#pragma unroll
        for (int it = 0; it < 4; ++it) {
            const int idx = it * 2048 + (tid << 2); // 0..8188, all multiples of 4
            const int bb = idx >> 7, kk = idx & 127;
            const float4 v = *(const float4*)(src + (size_t)bb * Hn + k0 + kk);
            sact[(kk + 0) * 65 + bb] = v.x;
            sact[(kk + 1) * 65 + bb] = v.y;
            sact[(kk + 2) * 65 + bb] = v.z;
            sact[(kk + 3) * 65 + bb] = v.w;
        }
        __syncthreads();
#pragma unroll 2
        for (int ch = s; ch < 32; ch += 2) {
            const int k = ch << 2;
            const float a0 = sact[(k + 0) * 65 + b], a1 = sact[(k + 1) * 65 + b];
            const float a2 = sact[(k + 2) * 65 + b], a3 = sact[(k + 3) * 65 + b];
#pragma unroll
            for (int jj = 0; jj < 4; ++jj) {
                const float4 w = *(const float4*)(wa + jj * Hn + k0 + k);
                accA[jj] = fmaf(w.x, a0, fmaf(w.y, a1, fmaf(w.z, a2, fmaf(w.w, a3, accA[jj]))));
            }
            if (HASB) {
#pragma unroll
                for (int jj = 0; jj < 4; ++jj) {
                    const float4 w = *(const float4*)(wb + jj * Hn + k0 + k);
                    accB[jj] = fmaf(w.x, a0, fmaf(w.y, a1, fmaf(w.z, a2, fmaf(w.w, a3, accB[jj]))));
                }
            }
        }
    }
}

__global__ __launch_bounds__(NTHR, 2) void aclstm_kernel(
    const float* __restrict__ xseq,
    const float* __restrict__ Wih1, const float* __restrict__ Whh1,
    const float* __restrict__ bih1, const float* __restrict__ bhh1,
    const float* __restrict__ Wih2, const float* __restrict__ Whh2,
    const float* __restrict__ bih2, const float* __restrict__ bhh2,
    const float* __restrict__ Wih3, const float* __restrict__ Whh3,
    const float* __restrict__ bih3, const float* __restrict__ bhh3,
    const float* __restrict__ Wd, const float* __restrict__ bd,
    const int* __restrict__ cnum_p, const int* __restrict__ gnum_p,
    float* __restrict__ hbuf, float* __restrict__ cbuf,
    float* __restrict__ outprev, float* __restrict__ dout,
    unsigned* __restrict__ bar) {
    __shared__ float sact[Fn * 65];    // 8580 floats: transposed act tile [k][b], stride 65
    __shared__ float gbuf[8 * 12 * 64]; // gate partials [s][g][unit][b]; reused as decoder reduce

    const int tid = threadIdx.x;
    const int bid = blockIdx.x;
    const int b = tid & 63;
    const int g = (tid >> 6) & 3;
    const int s = tid >> 8;
    const int j0 = bid << 2;

    const int gnum = gnum_p[0];
    const int per = gnum + cnum_p[0];

    // Per-thread bias sums (only the s==0 half carries the bias).
    float bsum[12];
    {
        const float* bihv[3] = {bih1, bih2, bih3};
        const float* bhhv[3] = {bhh1, bhh2, bhh3};
#pragma unroll
        for (int c0 = 0; c0 < 3; ++c0) {
#pragma unroll
            for (int jj = 0; jj < 4; ++jj) {
                const int row = g * Hn + j0 + jj;
                bsum[c0 * 4 + jj] = (s == 0) ? (bihv[c0][row] + bhhv[c0][row]) : 0.0f;
            }
        }
    }

    // Weight row bases for this thread's (gate g, columns j0..j0+3).
    const float* wI1 = Wih1 + (size_t)(g * Hn + j0) * Fn;
    const float* wH1 = Whh1 + (size_t)(g * Hn + j0) * Hn;
    const float* wI2 = Wih2 + (size_t)(g * Hn + j0) * Hn;
    const float* wH2 = Whh2 + (size_t)(g * Hn + j0) * Hn;
    const float* wI3 = Wih3 + (size_t)(g * Hn + j0) * Hn;
    const float* wH3 = Whh3 + (size_t)(g * Hn + j0) * Hn;

    unsigned ep = 0;
    int tmod = 0;
    for (int t = 0; t < Tn; ++t) {
        const int flag = (tmod < gnum) ? 1 : 0;
        const int tmodn = (tmod + 1 >= per) ? 0 : (tmod + 1);
        const float* h_old = hbuf + (size_t)(t & 1) * 3 * BH;
        float* h_new = hbuf + (size_t)((t + 1) & 1) * 3 * BH;

        float acc[12];
#pragma unroll
        for (int i = 0; i < 12; ++i) acc[i] = bsum[i];

        // S0: in_frame (teacher-forced frame or previous decoder output) -> cell0 via Wih1
        if (flag)
            do_xsrc(xseq + (size_t)t * Fn, Tn * Fn, wI1, acc + 0, sact, tid, b, s);
        else
            do_xsrc(outprev, Fn, wI1, acc + 0, sact, tid, b, s);
        // S1: old h0 -> cell0 via Whh1, cell1 via Wih2
        do_hsrc<true>(h_old, wH1, wI2, acc + 0, acc + 4, sact, tid, b, s);
        // S2: old h1 -> cell1 via Whh2, cell2 via Wih3
        do_hsrc<true>(h_old + BH, wH2, wI3, acc + 4, acc + 8, sact, tid, b, s);
        // S3: old h2 -> cell2 via Whh3
        do_hsrc<false>(h_old + 2 * BH, wH3, nullptr, acc + 8, nullptr, sact, tid, b, s);

        // Publish gate partials, combine K-halves, apply nonlinearities, update states.
#pragma unroll
        for (int i = 0; i < 12; ++i)
            gbuf[(((s << 2) | g) * 12 + i) * 64 + b] = acc[i];
        __syncthreads();

        for (int idx = tid; idx < 768; idx += NTHR) {
            const int i = idx >> 6, bb = idx & 63;
            const int cell = i >> 2;
            const int j = j0 + (i & 3);
            const float iv = gbuf[(0 * 12 + i) * 64 + bb] + gbuf[(4 * 12 + i) * 64 + bb];
            const float fv = gbuf[(1 * 12 + i) * 64 + bb] + gbuf[(5 * 12 + i) * 64 + bb];
            const float gv = gbuf[(2 * 12 + i) * 64 + bb] + gbuf[(6 * 12 + i) * 64 + bb];
            const float ov = gbuf[(3 * 12 + i) * 64 + bb] + gbuf[(7 * 12 + i) * 64 + bb];
            const int hidx = cell * BH + bb * Hn + j;
            const float cold = cbuf[hidx];
            const float cn = sigf(fv) * cold + sigf(iv) * tanhf(gv);
            cbuf[hidx] = cn;
            h_new[hidx] = sigf(ov) * tanhf(cn);
        }

        ++ep;
        gsync(bar, ep * NBLK); // states visible everywhere

        // Phase B: decoder out = h2_new @ Wd^T + bd. One block per feature f.
        if (bid < Fn) {
            const int f = bid;
            const int ss = tid >> 6; // 0..7 K-slices of 128
            const float* h2r = h_new + 2 * BH + (size_t)b * Hn;
            const float* wdr = Wd + (size_t)f * Hn;
            float p = 0.0f;
            const int kb = ss << 7;
#pragma unroll 4
            for (int k = kb; k < kb + 128; k += 4) {
                const float4 w = *(const float4*)(wdr + k);
                const float4 hv = *(const float4*)(h2r + k);
                p = fmaf(w.x, hv.x, fmaf(w.y, hv.y, fmaf(w.z, hv.z, fmaf(w.w, hv.w, p))));
            }
            gbuf[(ss << 6) + b] = p;
            __syncthreads();
            if (tid < 64) {
                float o = bd[f];
#pragma unroll
                for (int u = 0; u < 8; ++u) o += gbuf[(u << 6) + tid];
                dout[(size_t)tid * (Tn * Fn) + (size_t)t * Fn + f] = o;
                outprev[tid * Fn + f] = o;
            }
        }

        // Next step only reads outprev when it is autoregressive.
        const bool needbar = (t < Tn - 1) && (tmodn >= gnum);
        if (needbar) {
            ++ep;
            gsync(bar, ep * NBLK);
        }
        tmod = tmodn;
    }
}

extern "C" void kernel_launch(void* const* d_in, const int* in_sizes, int n_in,
                              void* d_out, int out_size, void* d_ws, size_t ws_size,
                              hipStream_t stream) {
    const float* xseq = (const float*)d_in[0];
    const float* Wih1 = (const float*)d_in[1];
    const float* Whh1 = (const float*)d_in[2];
    const float* bih1 = (const float*)d_in[3];
    const float* bhh1 = (const float*)d_in[4];
    const float* Wih2 = (const float*)d_in[5];
    const float* Whh2 = (const float*)d_in[6];
    const float* bih2 = (const float*)d_in[7];
    const float* bhh2 = (const float*)d_in[8];
    const float* Wih3 = (const float*)d_in[9];
    const float* Whh3 = (const float*)d_in[10];
    const float* bih3 = (const float*)d_in[11];
    const float* bhh3 = (const float*)d_in[12];
    const float* Wd = (const float*)d_in[13];
    const float* bd = (const float*)d_in[14];
    const int* cnum_p = (const int*)d_in[15];
    const int* gnum_p = (const int*)d_in[16];

    unsigned char* ws = (unsigned char*)d_ws;
    unsigned* bar = (unsigned*)ws;               // [0,256): barrier counter
    float* hbuf = (float*)(ws + 256);            // 2 buffers x 3 cells x B*H
    float* cbuf = hbuf + 2 * 3 * BH;             // 3 cells x B*H (in-place)
    float* outprev = cbuf + 3 * BH;              // B x F
    const size_t used = 256 + (size_t)(2 * 3 * BH + 3 * BH + Bn * Fn) * sizeof(float);

    // ws is re-poisoned before every timed launch: zero states + barrier each call.
    hipMemsetAsync(d_ws, 0, used, stream);

    hipLaunchKernelGGL(aclstm_kernel, dim3(NBLK), dim3(NTHR), 0, stream,
                       xseq, Wih1, Whh1, bih1, bhh1, Wih2, Whh2, bih2, bhh2,
                       Wih3, Whh3, bih3, bhh3, Wd, bd, cnum_p, gnum_p,
                       hbuf, cbuf, outprev, (float*)d_out, bar);
}

// Round 2
// 35694.278 us; speedup vs baseline: 4.5733x; 4.5733x over previous
//
#include <hip/hip_runtime.h>
#include <cstdint>

// Persistent fp16-MFMA 3-layer autoregressive LSTM. B=64,T=512,F=132,H=1024.
// Grid 256x512. Block owns j in [4bid,4bid+4) x 4 gates x 3 cells (48 gate rows).
// MFMA 16x16x32_f16: D[m=batch][n=16 gate-rows]. Waves = 4 m-tiles x 2 K-halves.
// Acts + weights pre-swizzled f16 so global_load_lds staging is coalesced and
// fragment ds_read_b128 is the canonical conflict-free pattern.

#define NBLK 256
#define NTHR 512
#define Bn 64
#define Tn 512
#define Fn 132
#define Hn 1024
#define TF (Tn * Fn)          // 67584
#define SRCH 65536            // halfs per h source (64*1024)
#define HBUF 196608           // halfs per h buffer (3 sources)
#define XTT 10240             // halfs per timestep of xT (20 k8 * 64 * 8)
#define WPB 84480             // halfs of weight blob per block (165 frags * 512)
#define NFRAG 165

typedef _Float16 h8 __attribute__((ext_vector_type(8)));
typedef float f4 __attribute__((ext_vector_type(4)));

__device__ __forceinline__ float sigf(float x) { return 1.0f / (1.0f + expf(-x)); }

__device__ __forceinline__ void gload16(const _Float16* g, _Float16* l) {
    __builtin_amdgcn_global_load_lds((const __attribute__((address_space(1))) unsigned int*)g,
                                     (__attribute__((address_space(3))) unsigned int*)l, 16, 0, 0);
}

__device__ __forceinline__ void gsync(unsigned* bar, unsigned target) {
    __syncthreads();
    if (threadIdx.x == 0) {
        __threadfence();
        __hip_atomic_fetch_add(bar, 1u, __ATOMIC_ACQ_REL, __HIP_MEMORY_SCOPE_AGENT);
        while (__hip_atomic_load(bar, __ATOMIC_ACQUIRE, __HIP_MEMORY_SCOPE_AGENT) < target) {
            __builtin_amdgcn_s_sleep(2);
        }
        __threadfence();
    }
    __syncthreads();
}

// ---------------- convert kernels (run once per launch, before persistent) ---

__global__ void k_bsum(const float* bih1, const float* bhh1, const float* bih2,
                       const float* bhh2, const float* bih3, const float* bhh3,
                       float* bsum) {
    int i = blockIdx.x * 256 + threadIdx.x;
    if (i >= NBLK * 48) return;
    int bidw = i / 48, r = i % 48;
    int cell = r >> 4, n = r & 15;
    int row = (n >> 2) * Hn + bidw * 4 + (n & 3);
    const float* bi = cell == 0 ? bih1 : (cell == 1 ? bih2 : bih3);
    const float* bh = cell == 0 ? bhh1 : (cell == 1 ? bhh2 : bhh3);
    bsum[i] = bi[row] + bh[row];
}

__global__ void k_convx(const float* xseq, _Float16* xT) {
    int i = blockIdx.x * 256 + threadIdx.x;
    if (i >= Tn * XTT) return;
    int t = i / XTT, r = i % XTT;
    int k8 = r >> 9, b = (r >> 3) & 63, e = r & 7;
    int f = k8 * 8 + e;
    float v = (f < Fn) ? xseq[((size_t)b * Tn + t) * Fn + f] : 0.0f;
    xT[i] = (_Float16)v;
}

__global__ void k_convw(const float* Wih1, const float* Whh1, const float* Wih2,
                        const float* Whh2, const float* Wih3, const float* Whh3,
                        _Float16* wblob) {
    int i = blockIdx.x * 256 + threadIdx.x;
    if (i >= NBLK * WPB) return;
    int bidw = i / WPB, r = i % WPB;
    int fidx = r >> 9, e = r & 511;
    int l = e >> 3, j = e & 7;
    int kq = l >> 4, n = l & 15;
    int row = (n >> 2) * Hn + bidw * 4 + (n & 3);
    const float* M;
    int K, k;
    if (fidx < 5) { // x-phase: Wih1, frags are kt 0..4 (chunk0: 0-3, chunk1: 4)
        M = Wih1; K = Fn;
        k = fidx * 32 + kq * 8 + j;
    } else if (fidx < 69) { // h0-phase: 8 chunks x [Whh1 kt0-3 | Wih2 kt0-3]
        int p = fidx - 5;
        int ch = p >> 3, cc = (p >> 2) & 1, kt = p & 3;
        M = cc ? Wih2 : Whh1; K = Hn;
        k = ch * 128 + kt * 32 + kq * 8 + j;
    } else if (fidx < 133) { // h1-phase: Whh2 | Wih3
        int p = fidx - 69;
        int ch = p >> 3, cc = (p >> 2) & 1, kt = p & 3;
        M = cc ? Wih3 : Whh2; K = Hn;
        k = ch * 128 + kt * 32 + kq * 8 + j;
    } else { // h2-phase: Whh3
        int p = fidx - 133;
        int ch = p >> 2, kt = p & 3;
        M = Whh3; K = Hn;
        k = ch * 128 + kt * 32 + kq * 8 + j;
    }
    float v = (k < K) ? M[(size_t)row * K + k] : 0.0f;
    wblob[i] = (_Float16)v;
}

__global__ void k_misc(_Float16* hT, _Float16* opT) {
    int i = blockIdx.x * 256 + threadIdx.x;
    if (i < HBUF) hT[i] = (_Float16)0.0f;           // zero h buffer 0 (t=0 reads it)
    else if (i < HBUF + XTT) opT[i - HBUF] = (_Float16)0.0f;
}

// ---------------- persistent kernel ----------------------------------------

__global__ __launch_bounds__(NTHR, 1) void lstm_mfma(
    const _Float16* __restrict__ xT, const _Float16* __restrict__ wblob,
    _Float16* __restrict__ hT, _Float16* __restrict__ opT,
    const float* __restrict__ bsum, const float* __restrict__ Wd,
    const float* __restrict__ bd, const int* __restrict__ cnum_p,
    const int* __restrict__ gnum_p, float* __restrict__ dout,
    unsigned* __restrict__ bar) {
    __shared__ _Float16 actb[2][8192];  // 16 k8 x 64 x 8, double-buffered (32 KB)
    __shared__ _Float16 wbs[2][4096];   // up to 8 frags x 512, double-buffered (16 KB)
    __shared__ float scr[3120];         // red [4][12][64] then gbuf [3][16][65] then decoder
    __shared__ float cst[768];          // c state [3][4][64] (block-private, persists)
    __shared__ float sbias[48];

    const int tid = threadIdx.x;
    const int bid = blockIdx.x;
    const int lane = tid & 63;
    const int wid = tid >> 6;
    const int kh = wid >> 2, mt = wid & 3;
    const int laneA = (lane >> 4) * 512 + (mt * 16 + (lane & 15)) * 8;
    const int laneB = lane * 8;

    if (tid < 48) sbias[tid] = bsum[bid * 48 + tid];
    for (int i = tid; i < 768; i += NTHR) cst[i] = 0.0f;
    __syncthreads();

    const int gnum = gnum_p[0];
    const int per = gnum + cnum_p[0];
    const _Float16* wbb = wblob + (size_t)bid * WPB;

    unsigned ep = 0;
    int tmod = 0;
    for (int t = 0; t < Tn; ++t) {
        const int flag = (tmod < gnum) ? 1 : 0;
        const int tmodn = (tmod + 1 >= per) ? 0 : (tmod + 1);
        const int rb = t % 3, wb2 = (t + 1) % 3;
        const _Float16* hr = hT + (size_t)rb * HBUF;
        _Float16* hw = hT + (size_t)wb2 * HBUF;
        const _Float16* xb = flag ? (xT + (size_t)t * XTT) : opT;

        f4 acc0 = {0.f, 0.f, 0.f, 0.f}, acc1 = acc0, acc2 = acc0;

        // ---- stage chunk helper (inlined via lambda) ----
        auto stage = [&](int c, int bsel) {
            int nact, nw, fb;
            const _Float16* ab;
            if (c < 2) {
                nact = c ? 4 : 16; nw = c ? 1 : 4; fb = c ? 4 : 0;
                ab = xb + c * 8192;
            } else if (c < 18) {
                int ph = (c - 2) >> 3, ch = (c - 2) & 7;
                nact = 16; nw = 8; fb = 5 + ph * 64 + ch * 8;
                ab = hr + ph * SRCH + ch * 8192;
            } else {
                int ch = c - 18;
                nact = 16; nw = 4; fb = 133 + ch * 4;
                ab = hr + 2 * SRCH + ch * 8192;
            }
            for (int i = wid; i < nact; i += 8)
                gload16(ab + i * 512 + laneB, &actb[bsel][i * 512]);
            for (int i = wid; i < nw; i += 8)
                gload16(wbb + (size_t)(fb + i) * 512 + laneB, &wbs[bsel][i * 512]);
        };

        stage(0, 0);
        for (int c = 0; c < 26; ++c) {
            const int cb = c & 1;
            __builtin_amdgcn_s_waitcnt(0x0f70); // vmcnt(0)
            __syncthreads();
            if (c < 25) stage(c + 1, cb ^ 1);
            // ---- consume chunk c ----
            if (c == 0) {
#pragma unroll
                for (int k2 = 0; k2 < 2; ++k2) {
                    int kt = kh * 2 + k2;
                    h8 a = *(const h8*)(&actb[cb][kt * 2048 + laneA]);
                    h8 b = *(const h8*)(&wbs[cb][kt * 512 + laneB]);
                    acc0 = __builtin_amdgcn_mfma_f32_16x16x32_f16(a, b, acc0, 0, 0, 0);
                }
            } else if (c == 1) {
                if (kh == 0) {
                    h8 a = *(const h8*)(&actb[cb][laneA]);
                    h8 b = *(const h8*)(&wbs[cb][laneB]);
                    acc0 = __builtin_amdgcn_mfma_f32_16x16x32_f16(a, b, acc0, 0, 0, 0);
                }
            } else if (c < 18) {
                const int ph = (c - 2) >> 3;
#pragma unroll
                for (int k2 = 0; k2 < 2; ++k2) {
                    int kt = kh * 2 + k2;
                    h8 a = *(const h8*)(&actb[cb][kt * 2048 + laneA]);
                    h8 b0 = *(const h8*)(&wbs[cb][kt * 512 + laneB]);
                    h8 b1 = *(const h8*)(&wbs[cb][(4 + kt) * 512 + laneB]);
                    if (ph == 0) {
                        acc0 = __builtin_amdgcn_mfma_f32_16x16x32_f16(a, b0, acc0, 0, 0, 0);
                        acc1 = __builtin_amdgcn_mfma_f32_16x16x32_f16(a, b1, acc1, 0, 0, 0);
                    } else {
                        acc1 = __builtin_amdgcn_mfma_f32_16x16x32_f16(a, b0, acc1, 0, 0, 0);
                        acc2 = __builtin_amdgcn_mfma_f32_16x16x32_f16(a, b1, acc2, 0, 0, 0);
                    }
                }
            } else {
#pragma unroll
                for (int k2 = 0; k2 < 2; ++k2) {
                    int kt = kh * 2 + k2;
                    h8 a = *(const h8*)(&actb[cb][kt * 2048 + laneA]);
                    h8 b = *(const h8*)(&wbs[cb][kt * 512 + laneB]);
                    acc2 = __builtin_amdgcn_mfma_f32_16x16x32_f16(a, b, acc2, 0, 0, 0);
                }
            }
        }

        // ---- epilogue: K-half reduce, gates, state update ----
        if (kh == 1) {
#pragma unroll
            for (int cc = 0; cc < 3; ++cc) {
                const f4& a = cc == 0 ? acc0 : (cc == 1 ? acc1 : acc2);
#pragma unroll
                for (int r = 0; r < 4; ++r)
                    scr[(mt * 12 + cc * 4 + r) * 64 + lane] = a[r];
            }
        }
        __syncthreads();
        if (kh == 0) {
#pragma unroll
            for (int cc = 0; cc < 3; ++cc) {
                f4& a = cc == 0 ? acc0 : (cc == 1 ? acc1 : acc2);
#pragma unroll
                for (int r = 0; r < 4; ++r)
                    a[r] += scr[(mt * 12 + cc * 4 + r) * 64 + lane];
            }
        }
        __syncthreads();
        if (kh == 0) {
            const int n = lane & 15, q = lane >> 4;
#pragma unroll
            for (int cc = 0; cc < 3; ++cc) {
                const f4& a = cc == 0 ? acc0 : (cc == 1 ? acc1 : acc2);
#pragma unroll
                for (int r = 0; r < 4; ++r)
                    scr[(cc * 16 + n) * 65 + mt * 16 + q * 4 + r] = a[r];
            }
        }
        __syncthreads();
        for (int idx = tid; idx < 768; idx += NTHR) {
            const int cell = idx >> 8, rr = idx & 255;
            const int jj = rr >> 6, b = rr & 63;
            const float iv = scr[(cell * 16 + 0 + jj) * 65 + b] + sbias[cell * 16 + jj];
            const float fv = scr[(cell * 16 + 4 + jj) * 65 + b] + sbias[cell * 16 + 4 + jj];
            const float gv = scr[(cell * 16 + 8 + jj) * 65 + b] + sbias[cell * 16 + 8 + jj];
            const float ov = scr[(cell * 16 + 12 + jj) * 65 + b] + sbias[cell * 16 + 12 + jj];
            const float cold = cst[(cell * 4 + jj) * 64 + b];
            const float cn = sigf(fv) * cold + sigf(iv) * tanhf(gv);
            cst[(cell * 4 + jj) * 64 + b] = cn;
            const float hn = sigf(ov) * tanhf(cn);
            const int j = 4 * bid + jj;
            hw[cell * SRCH + (j >> 3) * 512 + b * 8 + (j & 7)] = (_Float16)hn;
        }

        ++ep;
        gsync(bar, ep * NBLK); // all h_new visible

        // ---- decoder: out = h2_new @ Wd^T + bd (blocks 0..131) ----
        if (bid < Fn) {
            const _Float16* h2 = hT + (size_t)wb2 * HBUF + 2 * SRCH;
            const int ss = tid >> 6, b = tid & 63;
            const float* wdr = Wd + (size_t)bid * Hn;
            float p = 0.0f;
#pragma unroll 4
            for (int i = 0; i < 16; ++i) {
                const int k8 = ss * 16 + i;
                h8 hv = *(const h8*)(h2 + k8 * 512 + b * 8);
                const float4 w0 = *(const float4*)(wdr + k8 * 8);
                const float4 w1 = *(const float4*)(wdr + k8 * 8 + 4);
                p = fmaf((float)hv[0], w0.x, p); p = fmaf((float)hv[1], w0.y, p);
                p = fmaf((float)hv[2], w0.z, p); p = fmaf((float)hv[3], w0.w, p);
                p = fmaf((float)hv[4], w1.x, p); p = fmaf((float)hv[5], w1.y, p);
                p = fmaf((float)hv[6], w1.z, p); p = fmaf((float)hv[7], w1.w, p);
            }
            scr[ss * 64 + b] = p;
            __syncthreads();
            if (tid < 64) {
                float o = bd[bid];
#pragma unroll
                for (int u = 0; u < 8; ++u) o += scr[u * 64 + tid];
                dout[(size_t)tid * TF + (size_t)t * Fn + bid] = o;
                opT[(bid >> 3) * 512 + tid * 8 + (bid & 7)] = (_Float16)o;
            }
            __syncthreads(); // scr reused next step
        }

        const bool needbar = (t < Tn - 1) && (tmodn >= gnum);
        if (needbar) {
            ++ep;
            gsync(bar, ep * NBLK);
        }
        tmod = tmodn;
    }
}

// ---------------- host ------------------------------------------------------

extern "C" void kernel_launch(void* const* d_in, const int* in_sizes, int n_in,
                              void* d_out, int out_size, void* d_ws, size_t ws_size,
                              hipStream_t stream) {
    const float* xseq = (const float*)d_in[0];
    const float* Wih1 = (const float*)d_in[1];
    const float* Whh1 = (const float*)d_in[2];
    const float* bih1 = (const float*)d_in[3];
    const float* bhh1 = (const float*)d_in[4];
    const float* Wih2 = (const float*)d_in[5];
    const float* Whh2 = (const float*)d_in[6];
    const float* bih2 = (const float*)d_in[7];
    const float* bhh2 = (const float*)d_in[8];
    const float* Wih3 = (const float*)d_in[9];
    const float* Whh3 = (const float*)d_in[10];
    const float* bih3 = (const float*)d_in[11];
    const float* bhh3 = (const float*)d_in[12];
    const float* Wd = (const float*)d_in[13];
    const float* bd = (const float*)d_in[14];
    const int* cnum_p = (const int*)d_in[15];
    const int* gnum_p = (const int*)d_in[16];

    unsigned char* ws = (unsigned char*)d_ws;
    unsigned* bar = (unsigned*)ws;                       // 512 B
    float* bsum = (float*)(ws + 512);                    // 12288 f32 = 49152 B
    _Float16* xT = (_Float16*)(ws + 49664);              // 5,242,880 halfs
    _Float16* wblob = (_Float16*)(ws + 49664 + 10485760);        // 21,626,880 halfs
    _Float16* hT = (_Float16*)(ws + 49664 + 10485760 + 43253760); // 589,824 halfs
    _Float16* opT = (_Float16*)(ws + 49664 + 10485760 + 43253760 + 1179648); // 10,240 halfs

    hipMemsetAsync(bar, 0, 512, stream);
    hipLaunchKernelGGL(k_bsum, dim3((NBLK * 48 + 255) / 256), dim3(256), 0, stream,
                       bih1, bhh1, bih2, bhh2, bih3, bhh3, bsum);
    hipLaunchKernelGGL(k_convx, dim3((Tn * XTT + 255) / 256), dim3(256), 0, stream,
                       xseq, xT);
    hipLaunchKernelGGL(k_convw, dim3((NBLK * WPB + 255) / 256), dim3(256), 0, stream,
                       Wih1, Whh1, Wih2, Whh2, Wih3, Whh3, wblob);
    hipLaunchKernelGGL(k_misc, dim3((HBUF + XTT + 255) / 256), dim3(256), 0, stream,
                       hT, opT);
    hipLaunchKernelGGL(lstm_mfma, dim3(NBLK), dim3(NTHR), 0, stream,
                       xT, wblob, hT, opT, bsum, Wd, bd, cnum_p, gnum_p,
                       (float*)d_out, bar);
}

// Round 3
// 28568.195 us; speedup vs baseline: 5.7141x; 1.2494x over previous
//
#include <hip/hip_runtime.h>
#include <cstdint>

// Persistent fp16-MFMA 3-layer autoregressive LSTM. B=64,T=512,F=132,H=1024.
// Round 3: weight-stationary. Each block owns j in [4bid,4bid+4) x 4 gates x 3
// cells; its 165 B-fragments (84 VGPRs/lane) are loaded into registers ONCE and
// reused for all 512 steps. Waves = 8 K-slices; A-frags are loaded directly
// global->VGPR (coalesced 1KB/wave-load) with no LDS staging and no barriers
// inside the K-loop. 8-way cross-wave K-reduce once per step in LDS.

#define NBLK 256
#define NTHR 512
#define Bn 64
#define Tn 512
#define Fn 132
#define Hn 1024
#define TF (Tn * Fn)          // 67584
#define SRCH 65536            // halfs per h source (64*1024), layout [k8][b][8]
#define HBUF 196608           // halfs per h buffer (3 sources)
#define XTT 10240             // halfs per timestep of xT (20 k8 * 64 * 8)
#define WPB 86016             // halfs of weight blob per block (8 waves * 21 slots * 512)

typedef _Float16 h8 __attribute__((ext_vector_type(8)));
typedef float f4 __attribute__((ext_vector_type(4)));

__device__ __forceinline__ float sigf(float x) { return 1.0f / (1.0f + expf(-x)); }

__device__ __forceinline__ void gsync(unsigned* bar, unsigned target) {
    __syncthreads();
    if (threadIdx.x == 0) {
        __threadfence();
        __hip_atomic_fetch_add(bar, 1u, __ATOMIC_ACQ_REL, __HIP_MEMORY_SCOPE_AGENT);
        while (__hip_atomic_load(bar, __ATOMIC_ACQUIRE, __HIP_MEMORY_SCOPE_AGENT) < target) {
            __builtin_amdgcn_s_sleep(2);
        }
        __threadfence();
    }
    __syncthreads();
}

// ---------------- convert kernels (once per launch) -------------------------

__global__ void k_bsum(const float* bih1, const float* bhh1, const float* bih2,
                       const float* bhh2, const float* bih3, const float* bhh3,
                       float* bsum) {
    int i = blockIdx.x * 256 + threadIdx.x;
    if (i >= NBLK * 48) return;
    int bidw = i / 48, r = i % 48;
    int cell = r >> 4, n = r & 15;
    int row = (n >> 2) * Hn + bidw * 4 + (n & 3);
    const float* bi = cell == 0 ? bih1 : (cell == 1 ? bih2 : bih3);
    const float* bh = cell == 0 ? bhh1 : (cell == 1 ? bhh2 : bhh3);
    bsum[i] = bi[row] + bh[row];
}

__global__ void k_convx(const float* xseq, _Float16* xT) {
    int i = blockIdx.x * 256 + threadIdx.x;
    if (i >= Tn * XTT) return;
    int t = i / XTT, r = i % XTT;
    int k8 = r >> 9, b = (r >> 3) & 63, e = r & 7;
    int f = k8 * 8 + e;
    float v = (f < Fn) ? xseq[((size_t)b * Tn + t) * Fn + f] : 0.0f;
    xT[i] = (_Float16)v;
}

// Weight blob: [block][wave][slot 0..20][frag 512 halfs].
// slot 0-3: Whh1 kt=w*4+s  | 4-7: Wih2 | 8-11: Whh2 | 12-15: Wih3 | 16-19: Whh3
// slot 20: Wih1 kt=w (waves 0-4 only, else zero). Frag element (l=e>>3, j=e&7):
// B[k=kt*32+(l>>4)*8+j][n=l&15], row = (n>>2)*H + bid*4 + (n&3).
__global__ void k_convw(const float* Wih1, const float* Whh1, const float* Wih2,
                        const float* Whh2, const float* Wih3, const float* Whh3,
                        _Float16* wblob) {
    int i = blockIdx.x * 256 + threadIdx.x;
    if (i >= NBLK * WPB) return;
    int bidw = i / WPB, r = i % WPB;
    int slot = r >> 9, e = r & 511;
    int w = slot / 21, s = slot - w * 21;
    int l = e >> 3, j = e & 7;
    int kq = l >> 4, n = l & 15;
    int row = (n >> 2) * Hn + bidw * 4 + (n & 3);
    const float* M;
    int K, kt;
    if (s < 4)       { M = Whh1; K = Hn; kt = w * 4 + s; }
    else if (s < 8)  { M = Wih2; K = Hn; kt = w * 4 + s - 4; }
    else if (s < 12) { M = Whh2; K = Hn; kt = w * 4 + s - 8; }
    else if (s < 16) { M = Wih3; K = Hn; kt = w * 4 + s - 12; }
    else if (s < 20) { M = Whh3; K = Hn; kt = w * 4 + s - 16; }
    else             { M = Wih1; K = Fn; kt = w; }
    int k = kt * 32 + kq * 8 + j;
    float v = 0.0f;
    if (!(s == 20 && w >= 5) && k < K) v = M[(size_t)row * K + k];
    wblob[i] = (_Float16)v;
}

__global__ void k_misc(_Float16* hT, _Float16* opT) {
    int i = blockIdx.x * 256 + threadIdx.x;
    if (i < HBUF) hT[i] = (_Float16)0.0f;
    else if (i < HBUF + XTT) opT[i - HBUF] = (_Float16)0.0f;
}

// ---------------- persistent kernel ----------------------------------------

__global__ __launch_bounds__(NTHR, 2) void lstm_mfma(
    const _Float16* __restrict__ xT, const _Float16* __restrict__ wblob,
    _Float16* __restrict__ hT, _Float16* __restrict__ opT,
    const float* __restrict__ bsum, const float* __restrict__ Wd,
    const float* __restrict__ bd, const int* __restrict__ cnum_p,
    const int* __restrict__ gnum_p, float* __restrict__ dout,
    unsigned* __restrict__ bar) {
    // red[w][cc*4+mt][mq*17+n][r]: 8*12*68*4 floats = 102 KB. 17-stride swizzle
    // keeps reduce reads at 2-way banks. Also reused as decoder scratch.
    __shared__ float red[8 * 12 * 68 * 4];
    __shared__ float cst[768];   // c state [cell][jj][b], block-private
    __shared__ float sbias[48];

    const int tid = threadIdx.x;
    const int bid = blockIdx.x;
    const int lane = tid & 63;
    const int wid = tid >> 6;
    const int laneA0 = (lane >> 4) * 512 + (lane & 15) * 8;

    if (tid < 48) sbias[tid] = bsum[bid * 48 + tid];
    for (int i = tid; i < 768; i += NTHR) cst[i] = 0.0f;

    // Load this wave's 21 weight fragments into registers (84 VGPRs), once.
    h8 wfr[21];
    {
        const _Float16* wp = wblob + (size_t)bid * WPB + (size_t)(wid * 21) * 512 + lane * 8;
#pragma unroll
        for (int s2 = 0; s2 < 21; ++s2) wfr[s2] = *(const h8*)(wp + s2 * 512);
    }
    __syncthreads();

    const int gnum = gnum_p[0];
    const int per = gnum + cnum_p[0];

    unsigned ep = 0;
    int tmod = 0;
    for (int t = 0; t < Tn; ++t) {
        const int flag = (tmod < gnum) ? 1 : 0;
        const int tmodn = (tmod + 1 >= per) ? 0 : (tmod + 1);
        const int rb = t % 3, wb2 = (t + 1) % 3;
        const _Float16* hr = hT + (size_t)rb * HBUF;
        _Float16* hw = hT + (size_t)wb2 * HBUF;

        f4 acc[12]; // [cell][mt]
#pragma unroll
        for (int i = 0; i < 12; ++i) acc[i] = (f4){0.f, 0.f, 0.f, 0.f};

        // x phase: waves 0-4 cover K=160 (kt=wid), cell0.
        if (wid < 5) {
            const _Float16* xb = flag ? (xT + (size_t)t * XTT) : opT;
            const _Float16* x0 = xb + wid * 2048 + laneA0;
#pragma unroll
            for (int mt = 0; mt < 4; ++mt) {
                h8 a = *(const h8*)(x0 + mt * 128);
                acc[mt] = __builtin_amdgcn_mfma_f32_16x16x32_f16(a, wfr[20], acc[mt], 0, 0, 0);
            }
        }
        // h0: Whh1 -> cell0, Wih2 -> cell1 (shared A-frags)
        {
            const _Float16* s0 = hr + wid * 4 * 2048 + laneA0;
#pragma unroll
            for (int i2 = 0; i2 < 4; ++i2) {
#pragma unroll
                for (int mt = 0; mt < 4; ++mt) {
                    h8 a = *(const h8*)(s0 + i2 * 2048 + mt * 128);
                    acc[mt]     = __builtin_amdgcn_mfma_f32_16x16x32_f16(a, wfr[i2],     acc[mt],     0, 0, 0);
                    acc[4 + mt] = __builtin_amdgcn_mfma_f32_16x16x32_f16(a, wfr[4 + i2], acc[4 + mt], 0, 0, 0);
                }
            }
        }
        // h1: Whh2 -> cell1, Wih3 -> cell2
        {
            const _Float16* s1 = hr + SRCH + wid * 4 * 2048 + laneA0;
#pragma unroll
            for (int i2 = 0; i2 < 4; ++i2) {
#pragma unroll
                for (int mt = 0; mt < 4; ++mt) {
                    h8 a = *(const h8*)(s1 + i2 * 2048 + mt * 128);
                    acc[4 + mt] = __builtin_amdgcn_mfma_f32_16x16x32_f16(a, wfr[8 + i2],  acc[4 + mt], 0, 0, 0);
                    acc[8 + mt] = __builtin_amdgcn_mfma_f32_16x16x32_f16(a, wfr[12 + i2], acc[8 + mt], 0, 0, 0);
                }
            }
        }
        // h2: Whh3 -> cell2
        {
            const _Float16* s2 = hr + 2 * SRCH + wid * 4 * 2048 + laneA0;
#pragma unroll
            for (int i2 = 0; i2 < 4; ++i2) {
#pragma unroll
                for (int mt = 0; mt < 4; ++mt) {
                    h8 a = *(const h8*)(s2 + i2 * 2048 + mt * 128);
                    acc[8 + mt] = __builtin_amdgcn_mfma_f32_16x16x32_f16(a, wfr[16 + i2], acc[8 + mt], 0, 0, 0);
                }
            }
        }

        // ---- 8-way K-reduce + gates + state update ----
        {
            float* wr = red + ((size_t)(wid * 12) * 68 + (lane >> 4) * 17 + (lane & 15)) * 4;
#pragma unroll
            for (int cc = 0; cc < 3; ++cc)
#pragma unroll
                for (int mt = 0; mt < 4; ++mt)
                    *(f4*)(wr + (cc * 4 + mt) * 68 * 4) = acc[cc * 4 + mt];
        }
        __syncthreads();
        for (int idx = tid; idx < 768; idx += NTHR) {
            const int cell = idx >> 8, jj = (idx >> 6) & 3, b = idx & 63;
            const int mt = b >> 4, mq = (b >> 2) & 3, rr = b & 3;
            float gv4[4];
#pragma unroll
            for (int gt = 0; gt < 4; ++gt) {
                const int n = gt * 4 + jj;
                float v = sbias[cell * 16 + n];
#pragma unroll
                for (int w2 = 0; w2 < 8; ++w2)
                    v += red[(((w2 * 12 + cell * 4 + mt)) * 68 + mq * 17 + n) * 4 + rr];
                gv4[gt] = v;
            }
            const float cold = cst[(cell * 4 + jj) * 64 + b];
            const float cn = sigf(gv4[1]) * cold + sigf(gv4[0]) * tanhf(gv4[2]);
            cst[(cell * 4 + jj) * 64 + b] = cn;
            const float hn = sigf(gv4[3]) * tanhf(cn);
            const int j = 4 * bid + jj;
            hw[cell * SRCH + (j >> 3) * 512 + b * 8 + (j & 7)] = (_Float16)hn;
        }

        ++ep;
        gsync(bar, ep * NBLK); // all h_new visible device-wide

        // ---- decoder: out = h2_new @ Wd^T + bd (blocks 0..131) ----
        if (bid < Fn) {
            const _Float16* h2 = hT + (size_t)wb2 * HBUF + 2 * SRCH;
            const int ss = tid >> 6, b = tid & 63;
            const float* wdr = Wd + (size_t)bid * Hn;
            float p = 0.0f;
#pragma unroll 4
            for (int i = 0; i < 16; ++i) {
                const int k8 = ss * 16 + i;
                h8 hv = *(const h8*)(h2 + k8 * 512 + b * 8);
                const float4 w0 = *(const float4*)(wdr + k8 * 8);
                const float4 w1 = *(const float4*)(wdr + k8 * 8 + 4);
                p = fmaf((float)hv[0], w0.x, p); p = fmaf((float)hv[1], w0.y, p);
                p = fmaf((float)hv[2], w0.z, p); p = fmaf((float)hv[3], w0.w, p);
                p = fmaf((float)hv[4], w1.x, p); p = fmaf((float)hv[5], w1.y, p);
                p = fmaf((float)hv[6], w1.z, p); p = fmaf((float)hv[7], w1.w, p);
            }
            red[ss * 64 + b] = p;
            __syncthreads();
            if (tid < 64) {
                float o = bd[bid];
#pragma unroll
                for (int u = 0; u < 8; ++u) o += red[u * 64 + tid];
                dout[(size_t)tid * TF + (size_t)t * Fn + bid] = o;
                opT[(bid >> 3) * 512 + tid * 8 + (bid & 7)] = (_Float16)o;
            }
            __syncthreads(); // red reused next step
        }

        const bool needbar = (t < Tn - 1) && (tmodn >= gnum);
        if (needbar) {
            ++ep;
            gsync(bar, ep * NBLK);
        }
        tmod = tmodn;
    }
}

// ---------------- host ------------------------------------------------------

extern "C" void kernel_launch(void* const* d_in, const int* in_sizes, int n_in,
                              void* d_out, int out_size, void* d_ws, size_t ws_size,
                              hipStream_t stream) {
    const float* xseq = (const float*)d_in[0];
    const float* Wih1 = (const float*)d_in[1];
    const float* Whh1 = (const float*)d_in[2];
    const float* bih1 = (const float*)d_in[3];
    const float* bhh1 = (const float*)d_in[4];
    const float* Wih2 = (const float*)d_in[5];
    const float* Whh2 = (const float*)d_in[6];
    const float* bih2 = (const float*)d_in[7];
    const float* bhh2 = (const float*)d_in[8];
    const float* Wih3 = (const float*)d_in[9];
    const float* Whh3 = (const float*)d_in[10];
    const float* bih3 = (const float*)d_in[11];
    const float* bhh3 = (const float*)d_in[12];
    const float* Wd = (const float*)d_in[13];
    const float* bd = (const float*)d_in[14];
    const int* cnum_p = (const int*)d_in[15];
    const int* gnum_p = (const int*)d_in[16];

    unsigned char* ws = (unsigned char*)d_ws;
    unsigned* bar = (unsigned*)ws;                                  // 512 B
    float* bsum = (float*)(ws + 512);                               // 12288 f32
    _Float16* xT = (_Float16*)(ws + 49664);                         // 5,242,880 halfs
    _Float16* wblob = (_Float16*)(ws + 49664 + 10485760);           // 22,020,096 halfs
    _Float16* hT = (_Float16*)(ws + 49664 + 10485760 + 44040192);   // 589,824 halfs
    _Float16* opT = (_Float16*)(ws + 49664 + 10485760 + 44040192 + 1179648);

    hipMemsetAsync(bar, 0, 512, stream);
    hipLaunchKernelGGL(k_bsum, dim3((NBLK * 48 + 255) / 256), dim3(256), 0, stream,
                       bih1, bhh1, bih2, bhh2, bih3, bhh3, bsum);
    hipLaunchKernelGGL(k_convx, dim3((Tn * XTT + 255) / 256), dim3(256), 0, stream,
                       xseq, xT);
    hipLaunchKernelGGL(k_convw, dim3((NBLK * WPB + 255) / 256), dim3(256), 0, stream,
                       Wih1, Whh1, Wih2, Whh2, Wih3, Whh3, wblob);
    hipLaunchKernelGGL(k_misc, dim3((HBUF + XTT + 255) / 256), dim3(256), 0, stream,
                       hT, opT);
    hipLaunchKernelGGL(lstm_mfma, dim3(NBLK), dim3(NTHR), 0, stream,
                       xT, wblob, hT, opT, bsum, Wd, bd, cnum_p, gnum_p,
                       (float*)d_out, bar);
}

// Round 4
// 15094.695 us; speedup vs baseline: 10.8144x; 1.8926x over previous
//
#include <hip/hip_runtime.h>
#include <cstdint>

// Persistent fp16-MFMA 3-layer autoregressive LSTM. B=64,T=512,F=132,H=1024.
// Round 4: quiet grid barrier. R3 spent ~37us/barrier (768 barriers = whole
// runtime) because ACQUIRE spin-polls emitted buffer_inv every iteration and
// ACQ_REL RMWs added wbl2/inv per op. New barrier: two-level relaxed arrive
// (8 per-cacheline group counters -> done -> flag), relaxed flag poll with
// hedged acquire, exactly one release fence (wbl2) + one acquire fence (inv)
// per block per barrier. Weight-stationary MFMA core unchanged.

#define NBLK 256
#define NTHR 512
#define Bn 64
#define Tn 512
#define Fn 132
#define Hn 1024
#define TF (Tn * Fn)          // 67584
#define SRCH 65536            // halfs per h source (64*1024), layout [k8][b][8]
#define HBUF 196608           // halfs per h buffer (3 sources)
#define XTT 10240             // halfs per timestep of xT (20 k8 * 64 * 8)
#define WPB 86016             // halfs of weight blob per block (8 waves * 21 slots * 512)

typedef _Float16 h8 __attribute__((ext_vector_type(8)));
typedef float f4 __attribute__((ext_vector_type(4)));

__device__ __forceinline__ float sigf(float x) { return 1.0f / (1.0f + expf(-x)); }

// Quiet two-level grid barrier. bar layout (uints): cnt[g] at g*32 (one
// cacheline each, g = bid>>5), done at 256, flag at 288. ep is 1-based.
__device__ __forceinline__ void gsync(unsigned* bar, unsigned ep) {
    __syncthreads();
    if (threadIdx.x == 0) {
        __builtin_amdgcn_fence(__ATOMIC_RELEASE, "agent"); // drain stores + wbl2 (once)
        unsigned* cnt = bar + ((blockIdx.x >> 5) << 5);
        unsigned* done = bar + 256;
        unsigned* flag = bar + 288;
        unsigned old = __hip_atomic_fetch_add(cnt, 1u, __ATOMIC_RELAXED, __HIP_MEMORY_SCOPE_AGENT);
        if (old == 32u * ep - 1u) {
            unsigned d = __hip_atomic_fetch_add(done, 1u, __ATOMIC_RELAXED, __HIP_MEMORY_SCOPE_AGENT);
            if (d == 8u * ep - 1u)
                __hip_atomic_store(flag, ep, __ATOMIC_RELEASE, __HIP_MEMORY_SCOPE_AGENT);
        }
        int spin = 0;
        while (__hip_atomic_load(flag, __ATOMIC_RELAXED, __HIP_MEMORY_SCOPE_AGENT) < ep) {
            __builtin_amdgcn_s_sleep(1);
            if ((++spin & 63) == 0) // hedge: bounded staleness if relaxed load can cache
                (void)__hip_atomic_load(flag, __ATOMIC_ACQUIRE, __HIP_MEMORY_SCOPE_AGENT);
        }
        __builtin_amdgcn_fence(__ATOMIC_ACQUIRE, "agent"); // one inv for this CU/XCD
    }
    __syncthreads();
}

// ---------------- convert kernels (once per launch) -------------------------

__global__ void k_bsum(const float* bih1, const float* bhh1, const float* bih2,
                       const float* bhh2, const float* bih3, const float* bhh3,
                       float* bsum) {
    int i = blockIdx.x * 256 + threadIdx.x;
    if (i >= NBLK * 48) return;
    int bidw = i / 48, r = i % 48;
    int cell = r >> 4, n = r & 15;
    int row = (n >> 2) * Hn + bidw * 4 + (n & 3);
    const float* bi = cell == 0 ? bih1 : (cell == 1 ? bih2 : bih3);
    const float* bh = cell == 0 ? bhh1 : (cell == 1 ? bhh2 : bhh3);
    bsum[i] = bi[row] + bh[row];
}

__global__ void k_convx(const float* xseq, _Float16* xT) {
    int i = blockIdx.x * 256 + threadIdx.x;
    if (i >= Tn * XTT) return;
    int t = i / XTT, r = i % XTT;
    int k8 = r >> 9, b = (r >> 3) & 63, e = r & 7;
    int f = k8 * 8 + e;
    float v = (f < Fn) ? xseq[((size_t)b * Tn + t) * Fn + f] : 0.0f;
    xT[i] = (_Float16)v;
}

// Weight blob: [block][wave][slot 0..20][frag 512 halfs].
// slot 0-3: Whh1 kt=w*4+s | 4-7: Wih2 | 8-11: Whh2 | 12-15: Wih3 | 16-19: Whh3
// slot 20: Wih1 kt=w (waves 0-4 only, else zero). Frag element (l=e>>3, j=e&7):
// B[k=kt*32+(l>>4)*8+j][n=l&15], row = (n>>2)*H + bid*4 + (n&3).
__global__ void k_convw(const float* Wih1, const float* Whh1, const float* Wih2,
                        const float* Whh2, const float* Wih3, const float* Whh3,
                        _Float16* wblob) {
    int i = blockIdx.x * 256 + threadIdx.x;
    if (i >= NBLK * WPB) return;
    int bidw = i / WPB, r = i % WPB;
    int slot = r >> 9, e = r & 511;
    int w = slot / 21, s = slot - w * 21;
    int l = e >> 3, j = e & 7;
    int kq = l >> 4, n = l & 15;
    int row = (n >> 2) * Hn + bidw * 4 + (n & 3);
    const float* M;
    int K, kt;
    if (s < 4)       { M = Whh1; K = Hn; kt = w * 4 + s; }
    else if (s < 8)  { M = Wih2; K = Hn; kt = w * 4 + s - 4; }
    else if (s < 12) { M = Whh2; K = Hn; kt = w * 4 + s - 8; }
    else if (s < 16) { M = Wih3; K = Hn; kt = w * 4 + s - 12; }
    else if (s < 20) { M = Whh3; K = Hn; kt = w * 4 + s - 16; }
    else             { M = Wih1; K = Fn; kt = w; }
    int k = kt * 32 + kq * 8 + j;
    float v = 0.0f;
    if (!(s == 20 && w >= 5) && k < K) v = M[(size_t)row * K + k];
    wblob[i] = (_Float16)v;
}

__global__ void k_misc(_Float16* hT, _Float16* opT) {
    int i = blockIdx.x * 256 + threadIdx.x;
    if (i < HBUF) hT[i] = (_Float16)0.0f;
    else if (i < HBUF + XTT) opT[i - HBUF] = (_Float16)0.0f;
}

// ---------------- persistent kernel ----------------------------------------

__global__ __launch_bounds__(NTHR, 2) void lstm_mfma(
    const _Float16* __restrict__ xT, const _Float16* __restrict__ wblob,
    _Float16* __restrict__ hT, _Float16* __restrict__ opT,
    const float* __restrict__ bsum, const float* __restrict__ Wd,
    const float* __restrict__ bd, const int* __restrict__ cnum_p,
    const int* __restrict__ gnum_p, float* __restrict__ dout,
    unsigned* __restrict__ bar) {
    // red[w][cc*4+mt][mq*17+n][r]: 8*12*68*4 floats = 102 KB; 17-stride swizzle
    // keeps reduce reads at 2-way banks. Reused as decoder scratch.
    __shared__ float red[8 * 12 * 68 * 4];
    __shared__ float cst[768];   // c state [cell][jj][b], block-private
    __shared__ float sbias[48];

    const int tid = threadIdx.x;
    const int bid = blockIdx.x;
    const int lane = tid & 63;
    const int wid = tid >> 6;
    const int laneA0 = (lane >> 4) * 512 + (lane & 15) * 8;

    if (tid < 48) sbias[tid] = bsum[bid * 48 + tid];
    for (int i = tid; i < 768; i += NTHR) cst[i] = 0.0f;

    // Load this wave's 21 weight fragments into registers (84 VGPRs), once.
    h8 wfr[21];
    {
        const _Float16* wp = wblob + (size_t)bid * WPB + (size_t)(wid * 21) * 512 + lane * 8;
#pragma unroll
        for (int s2 = 0; s2 < 21; ++s2) wfr[s2] = *(const h8*)(wp + s2 * 512);
    }
    __syncthreads();

    const int gnum = gnum_p[0];
    const int per = gnum + cnum_p[0];

    unsigned ep = 0;
    int tmod = 0;
    for (int t = 0; t < Tn; ++t) {
        const int flag = (tmod < gnum) ? 1 : 0;
        const int tmodn = (tmod + 1 >= per) ? 0 : (tmod + 1);
        const int rb = t % 3, wb2 = (t + 1) % 3;
        const _Float16* hr = hT + (size_t)rb * HBUF;
        _Float16* hw = hT + (size_t)wb2 * HBUF;

        f4 acc[12]; // [cell][mt]
#pragma unroll
        for (int i = 0; i < 12; ++i) acc[i] = (f4){0.f, 0.f, 0.f, 0.f};

        // x phase: waves 0-4 cover K=160 (kt=wid), cell0.
        if (wid < 5) {
            const _Float16* xb = flag ? (xT + (size_t)t * XTT) : opT;
            const _Float16* x0 = xb + wid * 2048 + laneA0;
#pragma unroll
            for (int mt = 0; mt < 4; ++mt) {
                h8 a = *(const h8*)(x0 + mt * 128);
                acc[mt] = __builtin_amdgcn_mfma_f32_16x16x32_f16(a, wfr[20], acc[mt], 0, 0, 0);
            }
        }
        // h0: Whh1 -> cell0, Wih2 -> cell1 (shared A-frags)
        {
            const _Float16* s0 = hr + wid * 4 * 2048 + laneA0;
#pragma unroll
            for (int i2 = 0; i2 < 4; ++i2) {
#pragma unroll
                for (int mt = 0; mt < 4; ++mt) {
                    h8 a = *(const h8*)(s0 + i2 * 2048 + mt * 128);
                    acc[mt]     = __builtin_amdgcn_mfma_f32_16x16x32_f16(a, wfr[i2],     acc[mt],     0, 0, 0);
                    acc[4 + mt] = __builtin_amdgcn_mfma_f32_16x16x32_f16(a, wfr[4 + i2], acc[4 + mt], 0, 0, 0);
                }
            }
        }
        // h1: Whh2 -> cell1, Wih3 -> cell2
        {
            const _Float16* s1 = hr + SRCH + wid * 4 * 2048 + laneA0;
#pragma unroll
            for (int i2 = 0; i2 < 4; ++i2) {
#pragma unroll
                for (int mt = 0; mt < 4; ++mt) {
                    h8 a = *(const h8*)(s1 + i2 * 2048 + mt * 128);
                    acc[4 + mt] = __builtin_amdgcn_mfma_f32_16x16x32_f16(a, wfr[8 + i2],  acc[4 + mt], 0, 0, 0);
                    acc[8 + mt] = __builtin_amdgcn_mfma_f32_16x16x32_f16(a, wfr[12 + i2], acc[8 + mt], 0, 0, 0);
                }
            }
        }
        // h2: Whh3 -> cell2
        {
            const _Float16* s2 = hr + 2 * SRCH + wid * 4 * 2048 + laneA0;
#pragma unroll
            for (int i2 = 0; i2 < 4; ++i2) {
#pragma unroll
                for (int mt = 0; mt < 4; ++mt) {
                    h8 a = *(const h8*)(s2 + i2 * 2048 + mt * 128);
                    acc[8 + mt] = __builtin_amdgcn_mfma_f32_16x16x32_f16(a, wfr[16 + i2], acc[8 + mt], 0, 0, 0);
                }
            }
        }

        // ---- 8-way K-reduce + gates + state update ----
        {
            float* wr = red + ((size_t)(wid * 12) * 68 + (lane >> 4) * 17 + (lane & 15)) * 4;
#pragma unroll
            for (int cc = 0; cc < 3; ++cc)
#pragma unroll
                for (int mt = 0; mt < 4; ++mt)
                    *(f4*)(wr + (cc * 4 + mt) * 68 * 4) = acc[cc * 4 + mt];
        }
        __syncthreads();
        for (int idx = tid; idx < 768; idx += NTHR) {
            const int cell = idx >> 8, jj = (idx >> 6) & 3, b = idx & 63;
            const int mt = b >> 4, mq = (b >> 2) & 3, rr = b & 3;
            float gv4[4];
#pragma unroll
            for (int gt = 0; gt < 4; ++gt) {
                const int n = gt * 4 + jj;
                float v = sbias[cell * 16 + n];
#pragma unroll
                for (int w2 = 0; w2 < 8; ++w2)
                    v += red[(((w2 * 12 + cell * 4 + mt)) * 68 + mq * 17 + n) * 4 + rr];
                gv4[gt] = v;
            }
            const float cold = cst[(cell * 4 + jj) * 64 + b];
            const float cn = sigf(gv4[1]) * cold + sigf(gv4[0]) * tanhf(gv4[2]);
            cst[(cell * 4 + jj) * 64 + b] = cn;
            const float hn = sigf(gv4[3]) * tanhf(cn);
            const int j = 4 * bid + jj;
            __builtin_nontemporal_store((_Float16)hn,
                &hw[cell * SRCH + (j >> 3) * 512 + b * 8 + (j & 7)]);
        }

        ++ep;
        gsync(bar, ep); // all h_new visible device-wide

        // ---- decoder: out = h2_new @ Wd^T + bd (blocks 0..131) ----
        if (bid < Fn) {
            const _Float16* h2 = hT + (size_t)wb2 * HBUF + 2 * SRCH;
            const int ss = tid >> 6, b = tid & 63;
            const float* wdr = Wd + (size_t)bid * Hn;
            float p = 0.0f;
#pragma unroll 4
            for (int i = 0; i < 16; ++i) {
                const int k8 = ss * 16 + i;
                h8 hv = *(const h8*)(h2 + k8 * 512 + b * 8);
                const float4 w0 = *(const float4*)(wdr + k8 * 8);
                const float4 w1 = *(const float4*)(wdr + k8 * 8 + 4);
                p = fmaf((float)hv[0], w0.x, p); p = fmaf((float)hv[1], w0.y, p);
                p = fmaf((float)hv[2], w0.z, p); p = fmaf((float)hv[3], w0.w, p);
                p = fmaf((float)hv[4], w1.x, p); p = fmaf((float)hv[5], w1.y, p);
                p = fmaf((float)hv[6], w1.z, p); p = fmaf((float)hv[7], w1.w, p);
            }
            red[ss * 64 + b] = p;
            __syncthreads();
            if (tid < 64) {
                float o = bd[bid];
#pragma unroll
                for (int u = 0; u < 8; ++u) o += red[u * 64 + tid];
                __builtin_nontemporal_store(o, &dout[(size_t)tid * TF + (size_t)t * Fn + bid]);
                __builtin_nontemporal_store((_Float16)o,
                    &opT[(bid >> 3) * 512 + tid * 8 + (bid & 7)]);
            }
            __syncthreads(); // red reused next step
        }

        const bool needbar = (t < Tn - 1) && (tmodn >= gnum);
        if (needbar) {
            ++ep;
            gsync(bar, ep);
        }
        tmod = tmodn;
    }
}

// ---------------- host ------------------------------------------------------

extern "C" void kernel_launch(void* const* d_in, const int* in_sizes, int n_in,
                              void* d_out, int out_size, void* d_ws, size_t ws_size,
                              hipStream_t stream) {
    const float* xseq = (const float*)d_in[0];
    const float* Wih1 = (const float*)d_in[1];
    const float* Whh1 = (const float*)d_in[2];
    const float* bih1 = (const float*)d_in[3];
    const float* bhh1 = (const float*)d_in[4];
    const float* Wih2 = (const float*)d_in[5];
    const float* Whh2 = (const float*)d_in[6];
    const float* bih2 = (const float*)d_in[7];
    const float* bhh2 = (const float*)d_in[8];
    const float* Wih3 = (const float*)d_in[9];
    const float* Whh3 = (const float*)d_in[10];
    const float* bih3 = (const float*)d_in[11];
    const float* bhh3 = (const float*)d_in[12];
    const float* Wd = (const float*)d_in[13];
    const float* bd = (const float*)d_in[14];
    const int* cnum_p = (const int*)d_in[15];
    const int* gnum_p = (const int*)d_in[16];

    unsigned char* ws = (unsigned char*)d_ws;
    unsigned* bar = (unsigned*)ws;                                  // 4096 B
    float* bsum = (float*)(ws + 4096);                              // 12288 f32
    _Float16* xT = (_Float16*)(ws + 53248);                         // 5,242,880 halfs
    _Float16* wblob = (_Float16*)(ws + 53248 + 10485760);           // 22,020,096 halfs
    _Float16* hT = (_Float16*)(ws + 53248 + 10485760 + 44040192);   // 589,824 halfs
    _Float16* opT = (_Float16*)(ws + 53248 + 10485760 + 44040192 + 1179648);

    hipMemsetAsync(bar, 0, 4096, stream);
    hipLaunchKernelGGL(k_bsum, dim3((NBLK * 48 + 255) / 256), dim3(256), 0, stream,
                       bih1, bhh1, bih2, bhh2, bih3, bhh3, bsum);
    hipLaunchKernelGGL(k_convx, dim3((Tn * XTT + 255) / 256), dim3(256), 0, stream,
                       xseq, xT);
    hipLaunchKernelGGL(k_convw, dim3((NBLK * WPB + 255) / 256), dim3(256), 0, stream,
                       Wih1, Whh1, Wih2, Whh2, Wih3, Whh3, wblob);
    hipLaunchKernelGGL(k_misc, dim3((HBUF + XTT + 255) / 256), dim3(256), 0, stream,
                       hT, opT);
    hipLaunchKernelGGL(lstm_mfma, dim3(NBLK), dim3(NTHR), 0, stream,
                       xT, wblob, hT, opT, bsum, Wd, bd, cnum_p, gnum_p,
                       (float*)d_out, bar);
}

// Round 5
// 8837.292 us; speedup vs baseline: 18.4718x; 1.7081x over previous
//
#include <hip/hip_runtime.h>
#include <cstdint>

// Persistent fp16-MFMA 3-layer autoregressive LSTM. B=64,T=512,F=132,H=1024.
// Round 5: fence-free coherence. R4 spent ~19.6us/barrier almost entirely in
// per-block buffer_wbl2 + buffer_inv (full-L2 tag walks) and post-inv refills.
// Now ALL cross-block-mutable data (h, opT, barrier words) moves via relaxed
// AGENT-scope atomic loads/stores (sc0 sc1: bypass L1/L2, served at L3
// coherence point) -> zero cache-maintenance instructions. Read-only data
// (xT, weights, Wd) stays normally cached and remains L2-hot across steps.
// Barrier A: 2-level relaxed arrive (8 groups) + relaxed poll. Barrier B:
// producer-count barrier (132 decoder blocks arrive, everyone polls).

#define NBLK 256
#define NTHR 512
#define Bn 64
#define Tn 512
#define Fn 132
#define Hn 1024
#define TF (Tn * Fn)          // 67584
#define SRCH 65536            // halfs per h source (64*1024), layout [k8][b][8]
#define HBUF 196608           // halfs per h buffer (3 sources)
#define XTT 10240             // halfs per timestep of xT (20 k8 * 64 * 8)
#define WPB 86016             // halfs of weight blob per block (8 waves * 21 slots * 512)
#define OPW 160               // opT padded width (f32), cols 132..159 stay zero

typedef _Float16 h8 __attribute__((ext_vector_type(8)));
typedef float f4 __attribute__((ext_vector_type(4)));

__device__ __forceinline__ float sigf(float x) { return 1.0f / (1.0f + expf(-x)); }

// Coherent (agent-scope, L1/L2-bypassing) primitives. No fences anywhere.
__device__ __forceinline__ unsigned long long cload8(const void* p) {
    return __hip_atomic_load((unsigned long long*)p, __ATOMIC_RELAXED,
                             __HIP_MEMORY_SCOPE_AGENT);
}
__device__ __forceinline__ h8 cload16(const _Float16* p) {
    union { unsigned long long u[2]; h8 v; } c;
    c.u[0] = __hip_atomic_load((unsigned long long*)p, __ATOMIC_RELAXED,
                               __HIP_MEMORY_SCOPE_AGENT);
    c.u[1] = __hip_atomic_load((unsigned long long*)p + 1, __ATOMIC_RELAXED,
                               __HIP_MEMORY_SCOPE_AGENT);
    return c.v;
}
__device__ __forceinline__ void cstore8(void* p, unsigned long long v) {
    __hip_atomic_store((unsigned long long*)p, v, __ATOMIC_RELAXED,
                       __HIP_MEMORY_SCOPE_AGENT);
}
__device__ __forceinline__ void cstore4f(void* p, float v) {
    __hip_atomic_store((float*)p, v, __ATOMIC_RELAXED, __HIP_MEMORY_SCOPE_AGENT);
}

// Barrier A: all 256 blocks. bar layout (uints): cnt[g] at g*32 (g=bid>>5),
// done at 256, flag at 288. ep is 1-based. No fences: data moved via sc0/sc1
// accesses whose vmcnt completion precedes the arrival RMW in program order.
__device__ __forceinline__ void gsyncA(unsigned* bar, unsigned ep) {
    __syncthreads(); // compiler emits vmcnt(0) drain before s_barrier
    if (threadIdx.x == 0) {
        unsigned* cnt = bar + ((blockIdx.x >> 5) << 5);
        unsigned old = __hip_atomic_fetch_add(cnt, 1u, __ATOMIC_RELAXED,
                                              __HIP_MEMORY_SCOPE_AGENT);
        if (old == 32u * ep - 1u) {
            unsigned d = __hip_atomic_fetch_add(bar + 256, 1u, __ATOMIC_RELAXED,
                                                __HIP_MEMORY_SCOPE_AGENT);
            if (d == 8u * ep - 1u)
                __hip_atomic_store(bar + 288, ep, __ATOMIC_RELAXED,
                                   __HIP_MEMORY_SCOPE_AGENT);
        }
        while (__hip_atomic_load(bar + 288, __ATOMIC_RELAXED,
                                 __HIP_MEMORY_SCOPE_AGENT) < ep)
            __builtin_amdgcn_s_sleep(1);
    }
    __syncthreads();
}

// Barrier B: only decoder blocks (bid<132) arrive; everyone polls. bar2
// layout (uints): cnt[g] at g*32 (g=bid>>5, caps 32,32,32,32,4), done at 160,
// flag at 192. ep2 counts executed B-barriers (1-based).
__device__ __forceinline__ void gsyncB(unsigned* bar2, unsigned ep2) {
    __syncthreads();
    if (threadIdx.x == 0) {
        if (blockIdx.x < Fn) {
            const unsigned g = blockIdx.x >> 5;
            const unsigned cap = (g == 4) ? 4u : 32u;
            unsigned old = __hip_atomic_fetch_add(bar2 + g * 32, 1u,
                                                  __ATOMIC_RELAXED,
                                                  __HIP_MEMORY_SCOPE_AGENT);
            if (old == cap * ep2 - 1u) {
                unsigned d = __hip_atomic_fetch_add(bar2 + 160, 1u,
                                                    __ATOMIC_RELAXED,
                                                    __HIP_MEMORY_SCOPE_AGENT);
                if (d == 5u * ep2 - 1u)
                    __hip_atomic_store(bar2 + 192, ep2, __ATOMIC_RELAXED,
                                       __HIP_MEMORY_SCOPE_AGENT);
            }
        }
        while (__hip_atomic_load(bar2 + 192, __ATOMIC_RELAXED,
                                 __HIP_MEMORY_SCOPE_AGENT) < ep2)
            __builtin_amdgcn_s_sleep(1);
    }
    __syncthreads();
}

// ---------------- convert kernels (once per launch) -------------------------

__global__ void k_bsum(const float* bih1, const float* bhh1, const float* bih2,
                       const float* bhh2, const float* bih3, const float* bhh3,
                       float* bsum) {
    int i = blockIdx.x * 256 + threadIdx.x;
    if (i >= NBLK * 48) return;
    int bidw = i / 48, r = i % 48;
    int cell = r >> 4, n = r & 15;
    int row = (n >> 2) * Hn + bidw * 4 + (n & 3);
    const float* bi = cell == 0 ? bih1 : (cell == 1 ? bih2 : bih3);
    const float* bh = cell == 0 ? bhh1 : (cell == 1 ? bhh2 : bhh3);
    bsum[i] = bi[row] + bh[row];
}

__global__ void k_convx(const float* xseq, _Float16* xT) {
    int i = blockIdx.x * 256 + threadIdx.x;
    if (i >= Tn * XTT) return;
    int t = i / XTT, r = i % XTT;
    int k8 = r >> 9, b = (r >> 3) & 63, e = r & 7;
    int f = k8 * 8 + e;
    float v = (f < Fn) ? xseq[((size_t)b * Tn + t) * Fn + f] : 0.0f;
    xT[i] = (_Float16)v;
}

// Weight blob: [block][wave][slot 0..20][frag 512 halfs].
// slot 0-3: Whh1 kt=w*4+s | 4-7: Wih2 | 8-11: Whh2 | 12-15: Wih3 | 16-19: Whh3
// slot 20: Wih1 kt=w (waves 0-4 only, else zero). Frag element (l=e>>3, j=e&7):
// B[k=kt*32+(l>>4)*8+j][n=l&15], row = (n>>2)*H + bid*4 + (n&3).
__global__ void k_convw(const float* Wih1, const float* Whh1, const float* Wih2,
                        const float* Whh2, const float* Wih3, const float* Whh3,
                        _Float16* wblob) {
    int i = blockIdx.x * 256 + threadIdx.x;
    if (i >= NBLK * WPB) return;
    int bidw = i / WPB, r = i % WPB;
    int slot = r >> 9, e = r & 511;
    int w = slot / 21, s = slot - w * 21;
    int l = e >> 3, j = e & 7;
    int kq = l >> 4, n = l & 15;
    int row = (n >> 2) * Hn + bidw * 4 + (n & 3);
    const float* M;
    int K, kt;
    if (s < 4)       { M = Whh1; K = Hn; kt = w * 4 + s; }
    else if (s < 8)  { M = Wih2; K = Hn; kt = w * 4 + s - 4; }
    else if (s < 12) { M = Whh2; K = Hn; kt = w * 4 + s - 8; }
    else if (s < 16) { M = Wih3; K = Hn; kt = w * 4 + s - 12; }
    else if (s < 20) { M = Whh3; K = Hn; kt = w * 4 + s - 16; }
    else             { M = Wih1; K = Fn; kt = w; }
    int k = kt * 32 + kq * 8 + j;
    float v = 0.0f;
    if (!(s == 20 && w >= 5) && k < K) v = M[(size_t)row * K + k];
    wblob[i] = (_Float16)v;
}

__global__ void k_misc(_Float16* hT, float* opT) {
    int i = blockIdx.x * 256 + threadIdx.x;
    if (i < HBUF) hT[i] = (_Float16)0.0f;
    else if (i < HBUF + Bn * OPW) opT[i - HBUF] = 0.0f;
}

// ---------------- persistent kernel ----------------------------------------

__global__ __launch_bounds__(NTHR, 2) void lstm_mfma(
    const _Float16* __restrict__ xT, const _Float16* __restrict__ wblob,
    _Float16* __restrict__ hT, float* __restrict__ opT,
    const float* __restrict__ bsum, const float* __restrict__ Wd,
    const float* __restrict__ bd, const int* __restrict__ cnum_p,
    const int* __restrict__ gnum_p, float* __restrict__ dout,
    unsigned* __restrict__ bar) {
    // red[w][cc*4+mt][mq*17+n][r]: 8*12*68*4 floats = 102 KB; 17-stride swizzle
    // keeps reduce reads at 2-way banks. Reused as decoder scratch.
    __shared__ float red[8 * 12 * 68 * 4];
    __shared__ float cst[768];                 // c state [cell][jj][b], block-private
    __shared__ float sbias[48];
    __shared__ unsigned long long hstage[192]; // h packing stage [cell][b] -> 4 halfs

    const int tid = threadIdx.x;
    const int bid = blockIdx.x;
    const int lane = tid & 63;
    const int wid = tid >> 6;
    const int laneA0 = (lane >> 4) * 512 + (lane & 15) * 8;
    unsigned* bar2 = bar + 512;

    if (tid < 48) sbias[tid] = bsum[bid * 48 + tid];
    for (int i = tid; i < 768; i += NTHR) cst[i] = 0.0f;

    // Load this wave's 21 weight fragments into registers, once.
    h8 wfr[21];
    {
        const _Float16* wp = wblob + (size_t)bid * WPB + (size_t)(wid * 21) * 512 + lane * 8;
#pragma unroll
        for (int s2 = 0; s2 < 21; ++s2) wfr[s2] = *(const h8*)(wp + s2 * 512);
    }
    __syncthreads();

    const int gnum = gnum_p[0];
    const int per = gnum + cnum_p[0];

    unsigned epA = 0, epB = 0;
    int tmod = 0;
    for (int t = 0; t < Tn; ++t) {
        const int flag = (tmod < gnum) ? 1 : 0;
        const int tmodn = (tmod + 1 >= per) ? 0 : (tmod + 1);
        const int rb = t % 3, wb2 = (t + 1) % 3;
        const _Float16* hr = hT + (size_t)rb * HBUF;
        _Float16* hw = hT + (size_t)wb2 * HBUF;

        f4 acc[12]; // [cell][mt]
#pragma unroll
        for (int i = 0; i < 12; ++i) acc[i] = (f4){0.f, 0.f, 0.f, 0.f};

        // x phase: waves 0-4 cover K=160 (kt=wid), cell0.
        if (wid < 5) {
            if (flag) {
                const _Float16* x0 = xT + (size_t)t * XTT + wid * 2048 + laneA0;
#pragma unroll
                for (int mt = 0; mt < 4; ++mt) {
                    h8 a = *(const h8*)(x0 + mt * 128);
                    acc[mt] = __builtin_amdgcn_mfma_f32_16x16x32_f16(a, wfr[20], acc[mt], 0, 0, 0);
                }
            } else {
                // in_frame from opT (f32, coherent), convert to f16 frags.
                const float* op0 = opT + (size_t)(lane & 15) * OPW + wid * 32 + (lane >> 4) * 8;
#pragma unroll
                for (int mt = 0; mt < 4; ++mt) {
                    const float* q = op0 + (size_t)(mt * 16) * OPW;
                    h8 a;
#pragma unroll
                    for (int e2 = 0; e2 < 4; ++e2) {
                        union { unsigned long long u; float f[2]; } c;
                        c.u = cload8(q + 2 * e2);
                        a[2 * e2] = (_Float16)c.f[0];
                        a[2 * e2 + 1] = (_Float16)c.f[1];
                    }
                    acc[mt] = __builtin_amdgcn_mfma_f32_16x16x32_f16(a, wfr[20], acc[mt], 0, 0, 0);
                }
            }
        }
        // h0: Whh1 -> cell0, Wih2 -> cell1 (shared A-frags, coherent loads)
        {
            const _Float16* s0 = hr + wid * 4 * 2048 + laneA0;
#pragma unroll
            for (int i2 = 0; i2 < 4; ++i2) {
#pragma unroll
                for (int mt = 0; mt < 4; ++mt) {
                    h8 a = cload16(s0 + i2 * 2048 + mt * 128);
                    acc[mt]     = __builtin_amdgcn_mfma_f32_16x16x32_f16(a, wfr[i2],     acc[mt],     0, 0, 0);
                    acc[4 + mt] = __builtin_amdgcn_mfma_f32_16x16x32_f16(a, wfr[4 + i2], acc[4 + mt], 0, 0, 0);
                }
            }
        }
        // h1: Whh2 -> cell1, Wih3 -> cell2
        {
            const _Float16* s1 = hr + SRCH + wid * 4 * 2048 + laneA0;
#pragma unroll
            for (int i2 = 0; i2 < 4; ++i2) {
#pragma unroll
                for (int mt = 0; mt < 4; ++mt) {
                    h8 a = cload16(s1 + i2 * 2048 + mt * 128);
                    acc[4 + mt] = __builtin_amdgcn_mfma_f32_16x16x32_f16(a, wfr[8 + i2],  acc[4 + mt], 0, 0, 0);
                    acc[8 + mt] = __builtin_amdgcn_mfma_f32_16x16x32_f16(a, wfr[12 + i2], acc[8 + mt], 0, 0, 0);
                }
            }
        }
        // h2: Whh3 -> cell2
        {
            const _Float16* s2 = hr + 2 * SRCH + wid * 4 * 2048 + laneA0;
#pragma unroll
            for (int i2 = 0; i2 < 4; ++i2) {
#pragma unroll
                for (int mt = 0; mt < 4; ++mt) {
                    h8 a = cload16(s2 + i2 * 2048 + mt * 128);
                    acc[8 + mt] = __builtin_amdgcn_mfma_f32_16x16x32_f16(a, wfr[16 + i2], acc[8 + mt], 0, 0, 0);
                }
            }
        }

        // ---- 8-way K-reduce + gates + state update ----
        {
            float* wr = red + ((size_t)(wid * 12) * 68 + (lane >> 4) * 17 + (lane & 15)) * 4;
#pragma unroll
            for (int cc = 0; cc < 3; ++cc)
#pragma unroll
                for (int mt = 0; mt < 4; ++mt)
                    *(f4*)(wr + (cc * 4 + mt) * 68 * 4) = acc[cc * 4 + mt];
        }
        __syncthreads();
        for (int idx = tid; idx < 768; idx += NTHR) {
            const int cell = idx >> 8, jj = (idx >> 6) & 3, b = idx & 63;
            const int mt = b >> 4, mq = (b >> 2) & 3, rr = b & 3;
            float gv4[4];
#pragma unroll
            for (int gt = 0; gt < 4; ++gt) {
                const int n = gt * 4 + jj;
                float v = sbias[cell * 16 + n];
#pragma unroll
                for (int w2 = 0; w2 < 8; ++w2)
                    v += red[(((w2 * 12 + cell * 4 + mt)) * 68 + mq * 17 + n) * 4 + rr];
                gv4[gt] = v;
            }
            const float cold = cst[(cell * 4 + jj) * 64 + b];
            const float cn = sigf(gv4[1]) * cold + sigf(gv4[0]) * tanhf(gv4[2]);
            cst[(cell * 4 + jj) * 64 + b] = cn;
            const float hn = sigf(gv4[3]) * tanhf(cn);
            ((_Float16*)hstage)[(cell * 64 + b) * 4 + jj] = (_Float16)hn;
        }
        __syncthreads();
        if (tid < 192) { // pack 4 halfs -> one coherent 8B store
            const int cell = tid >> 6, b = tid & 63;
            _Float16* dst = hw + cell * SRCH + (bid >> 1) * 512 + b * 8 + 4 * (bid & 1);
            cstore8(dst, hstage[tid]);
        }

        ++epA;
        gsyncA(bar, epA); // all h_new at coherence point, visible via cloads

        // ---- decoder: out = h2_new @ Wd^T + bd (blocks 0..131) ----
        if (bid < Fn) {
            const _Float16* h2 = hT + (size_t)wb2 * HBUF + 2 * SRCH;
            const int ss = tid >> 6, b = tid & 63;
            const float* wdr = Wd + (size_t)bid * Hn;
            float p = 0.0f;
#pragma unroll 4
            for (int i = 0; i < 16; ++i) {
                const int k8 = ss * 16 + i;
                h8 hv = cload16(h2 + k8 * 512 + b * 8);
                const float4 w0 = *(const float4*)(wdr + k8 * 8);
                const float4 w1 = *(const float4*)(wdr + k8 * 8 + 4);
                p = fmaf((float)hv[0], w0.x, p); p = fmaf((float)hv[1], w0.y, p);
                p = fmaf((float)hv[2], w0.z, p); p = fmaf((float)hv[3], w0.w, p);
                p = fmaf((float)hv[4], w1.x, p); p = fmaf((float)hv[5], w1.y, p);
                p = fmaf((float)hv[6], w1.z, p); p = fmaf((float)hv[7], w1.w, p);
            }
            red[ss * 64 + b] = p;
            __syncthreads();
            if (tid < 64) {
                float o = bd[bid];
#pragma unroll
                for (int u = 0; u < 8; ++u) o += red[u * 64 + tid];
                __builtin_nontemporal_store(o, &dout[(size_t)tid * TF + (size_t)t * Fn + bid]);
                cstore4f(&opT[(size_t)tid * OPW + bid], o);
            }
            __syncthreads(); // red reused next step
        }

        // Next step reads opT only when autoregressive.
        const bool needbar = (t < Tn - 1) && (tmodn >= gnum);
        if (needbar) {
            ++epB;
            gsyncB(bar2, epB);
        }
        tmod = tmodn;
    }
}

// ---------------- host ------------------------------------------------------

extern "C" void kernel_launch(void* const* d_in, const int* in_sizes, int n_in,
                              void* d_out, int out_size, void* d_ws, size_t ws_size,
                              hipStream_t stream) {
    const float* xseq = (const float*)d_in[0];
    const float* Wih1 = (const float*)d_in[1];
    const float* Whh1 = (const float*)d_in[2];
    const float* bih1 = (const float*)d_in[3];
    const float* bhh1 = (const float*)d_in[4];
    const float* Wih2 = (const float*)d_in[5];
    const float* Whh2 = (const float*)d_in[6];
    const float* bih2 = (const float*)d_in[7];
    const float* bhh2 = (const float*)d_in[8];
    const float* Wih3 = (const float*)d_in[9];
    const float* Whh3 = (const float*)d_in[10];
    const float* bih3 = (const float*)d_in[11];
    const float* bhh3 = (const float*)d_in[12];
    const float* Wd = (const float*)d_in[13];
    const float* bd = (const float*)d_in[14];
    const int* cnum_p = (const int*)d_in[15];
    const int* gnum_p = (const int*)d_in[16];

    unsigned char* ws = (unsigned char*)d_ws;
    unsigned* bar = (unsigned*)ws;                                  // 4096 B (A at +0, B at uint 512)
    float* bsum = (float*)(ws + 4096);                              // 12288 f32
    _Float16* xT = (_Float16*)(ws + 53248);                         // 5,242,880 halfs
    _Float16* wblob = (_Float16*)(ws + 53248 + 10485760);           // 22,020,096 halfs
    _Float16* hT = (_Float16*)(ws + 53248 + 10485760 + 44040192);   // 589,824 halfs
    float* opT = (float*)(ws + 53248 + 10485760 + 44040192 + 1179648); // 64*160 f32

    hipMemsetAsync(bar, 0, 4096, stream);
    hipLaunchKernelGGL(k_bsum, dim3((NBLK * 48 + 255) / 256), dim3(256), 0, stream,
                       bih1, bhh1, bih2, bhh2, bih3, bhh3, bsum);
    hipLaunchKernelGGL(k_convx, dim3((Tn * XTT + 255) / 256), dim3(256), 0, stream,
                       xseq, xT);
    hipLaunchKernelGGL(k_convw, dim3((NBLK * WPB + 255) / 256), dim3(256), 0, stream,
                       Wih1, Whh1, Wih2, Whh2, Wih3, Whh3, wblob);
    hipLaunchKernelGGL(k_misc, dim3((HBUF + Bn * OPW + 255) / 256), dim3(256), 0, stream,
                       hT, opT);
    hipLaunchKernelGGL(lstm_mfma, dim3(NBLK), dim3(NTHR), 0, stream,
                       xT, wblob, hT, opT, bsum, Wd, bd, cnum_p, gnum_p,
                       (float*)d_out, bar);
}

// Round 6
// 8587.494 us; speedup vs baseline: 19.0091x; 1.0291x over previous
//
#include <hip/hip_runtime.h>
#include <cstdint>

// Persistent fp16-MFMA 3-layer autoregressive LSTM. B=64,T=512,F=132,H=1024.
// Round 6: fuse the decoder into the recurrence. For AR steps,
// in_frame @ Wih1^T == h2_prev @ (Wih1@Wd)^T + (Wih1@bd), so precomputing
// W1d = Wih1@Wd lets the AR x-contribution ride on the SAME h2 fragments the
// Whh3 phase already loads -> barrier B deleted (512 barriers, was 768), and
// the dout decoder moves fully off the critical path (264 (f,K-half) jobs
// spread over all 256 blocks, atomicAdd into zeroed d_out, overlapping the
// next step's h-phase). Fence-free agent-scope coherence as in R5.

#define NBLK 256
#define NTHR 512
#define Bn 64
#define Tn 512
#define Fn 132
#define Hn 1024
#define TF (Tn * Fn)          // 67584
#define SRCH 65536            // halfs per h source (64*1024), layout [k8][b][8]
#define HBUF 196608           // halfs per h buffer (3 sources)
#define XTT 10240             // halfs per timestep of xT (20 k8 * 64 * 8)
#define WPB 102400            // halfs of weight blob per block (8 waves * 25 slots * 512)

typedef _Float16 h8 __attribute__((ext_vector_type(8)));
typedef float f4 __attribute__((ext_vector_type(4)));

__device__ __forceinline__ float sigf(float x) { return 1.0f / (1.0f + expf(-x)); }

// Coherent (agent-scope, L1/L2-bypassing) primitives. No fences anywhere.
__device__ __forceinline__ h8 cload16(const _Float16* p) {
    union { unsigned long long u[2]; h8 v; } c;
    c.u[0] = __hip_atomic_load((unsigned long long*)p, __ATOMIC_RELAXED,
                               __HIP_MEMORY_SCOPE_AGENT);
    c.u[1] = __hip_atomic_load((unsigned long long*)p + 1, __ATOMIC_RELAXED,
                               __HIP_MEMORY_SCOPE_AGENT);
    return c.v;
}
__device__ __forceinline__ void cstore8(void* p, unsigned long long v) {
    __hip_atomic_store((unsigned long long*)p, v, __ATOMIC_RELAXED,
                       __HIP_MEMORY_SCOPE_AGENT);
}

// Grid barrier: 2-level relaxed arrive (8 group lines) + relaxed poll.
__device__ __forceinline__ void gsyncA(unsigned* bar, unsigned ep) {
    __syncthreads(); // vmcnt drain of prior coherent stores precedes arrival
    if (threadIdx.x == 0) {
        unsigned* cnt = bar + ((blockIdx.x >> 5) << 5);
        unsigned old = __hip_atomic_fetch_add(cnt, 1u, __ATOMIC_RELAXED,
                                              __HIP_MEMORY_SCOPE_AGENT);
        if (old == 32u * ep - 1u) {
            unsigned d = __hip_atomic_fetch_add(bar + 256, 1u, __ATOMIC_RELAXED,
                                                __HIP_MEMORY_SCOPE_AGENT);
            if (d == 8u * ep - 1u)
                __hip_atomic_store(bar + 288, ep, __ATOMIC_RELAXED,
                                   __HIP_MEMORY_SCOPE_AGENT);
        }
        while (__hip_atomic_load(bar + 288, __ATOMIC_RELAXED,
                                 __HIP_MEMORY_SCOPE_AGENT) < ep)
            __builtin_amdgcn_s_sleep(1);
    }
    __syncthreads();
}

// ---------------- convert kernels (once per launch) -------------------------

// bsum[bid*48 + cell*16 + n] = bih+bhh for that gate row;
// bsum2[bid*16 + n] = sum_f Wih1[row,f]*bd[f]  (cell0 only, AR fused bias).
__global__ void k_bsum(const float* bih1, const float* bhh1, const float* bih2,
                       const float* bhh2, const float* bih3, const float* bhh3,
                       const float* Wih1, const float* bd,
                       float* bsum, float* bsum2) {
    int i = blockIdx.x * 256 + threadIdx.x;
    if (i < NBLK * 48) {
        int bidw = i / 48, r = i % 48;
        int cell = r >> 4, n = r & 15;
        int row = (n >> 2) * Hn + bidw * 4 + (n & 3);
        const float* bi = cell == 0 ? bih1 : (cell == 1 ? bih2 : bih3);
        const float* bh = cell == 0 ? bhh1 : (cell == 1 ? bhh2 : bhh3);
        bsum[i] = bi[row] + bh[row];
    } else if (i < NBLK * 64) {
        int ii = i - NBLK * 48;
        int bidw = ii / 16, n = ii % 16;
        int row = (n >> 2) * Hn + bidw * 4 + (n & 3);
        float s = 0.0f;
        for (int f = 0; f < Fn; ++f) s += Wih1[(size_t)row * Fn + f] * bd[f];
        bsum2[bidw * 16 + n] = s;
    }
}

__global__ void k_convx(const float* xseq, _Float16* xT) {
    int i = blockIdx.x * 256 + threadIdx.x;
    if (i >= Tn * XTT) return;
    int t = i / XTT, r = i % XTT;
    int k8 = r >> 9, b = (r >> 3) & 63, e = r & 7;
    int f = k8 * 8 + e;
    float v = (f < Fn) ? xseq[((size_t)b * Tn + t) * Fn + f] : 0.0f;
    xT[i] = (_Float16)v;
}

// Weight blob: [block][wave][slot 0..24][frag 512 halfs].
// slot 0-3: Whh1 kt=w*4+s | 4-7: Wih2 | 8-11: Whh2 | 12-15: Wih3 | 16-19: Whh3
// slot 20: Wih1 kt=w (waves 0-4) | slot 21-24: W1d = Wih1@Wd, kt=w*4+(s-21)
// (computed on the fly, 132-MAC dot). Frag element (l=e>>3, j=e&7):
// B[k=kt*32+(l>>4)*8+j][n=l&15], row = (n>>2)*H + bid*4 + (n&3).
__global__ void k_convw(const float* Wih1, const float* Whh1, const float* Wih2,
                        const float* Whh2, const float* Wih3, const float* Whh3,
                        const float* Wd, _Float16* wblob) {
    int i = blockIdx.x * 256 + threadIdx.x;
    if (i >= NBLK * WPB) return;
    int bidw = i / WPB, r = i % WPB;
    int slot = r >> 9, e = r & 511;
    int w = slot / 25, s = slot - w * 25;
    int l = e >> 3, j = e & 7;
    int kq = l >> 4, n = l & 15;
    int row = (n >> 2) * Hn + bidw * 4 + (n & 3);
    float v = 0.0f;
    if (s >= 21) { // fused W1d[r,k] = sum_f Wih1[r,f] * Wd[f,k]
        int kt = w * 4 + (s - 21);
        int k = kt * 32 + kq * 8 + j;
        float acc = 0.0f;
        for (int f = 0; f < Fn; ++f)
            acc += Wih1[(size_t)row * Fn + f] * Wd[(size_t)f * Hn + k];
        v = acc;
    } else {
        const float* M;
        int K, kt;
        if (s < 4)       { M = Whh1; K = Hn; kt = w * 4 + s; }
        else if (s < 8)  { M = Wih2; K = Hn; kt = w * 4 + s - 4; }
        else if (s < 12) { M = Whh2; K = Hn; kt = w * 4 + s - 8; }
        else if (s < 16) { M = Wih3; K = Hn; kt = w * 4 + s - 12; }
        else if (s < 20) { M = Whh3; K = Hn; kt = w * 4 + s - 16; }
        else             { M = Wih1; K = Fn; kt = w; }
        int k = kt * 32 + kq * 8 + j;
        if (!(s == 20 && w >= 5) && k < K) v = M[(size_t)row * K + k];
    }
    wblob[i] = (_Float16)v;
}

__global__ void k_misc(_Float16* hT) {
    int i = blockIdx.x * 256 + threadIdx.x;
    if (i < HBUF) hT[i] = (_Float16)0.0f;
}

// ---------------- persistent kernel ----------------------------------------

__global__ __launch_bounds__(NTHR, 2) void lstm_mfma(
    const _Float16* __restrict__ xT, const _Float16* __restrict__ wblob,
    _Float16* __restrict__ hT, const float* __restrict__ bsum,
    const float* __restrict__ bsum2, const float* __restrict__ Wd,
    const float* __restrict__ bd, const int* __restrict__ cnum_p,
    const int* __restrict__ gnum_p, float* __restrict__ dout,
    unsigned* __restrict__ bar) {
    // red[w][cc*4+mt][mq*17+n][r]: 8*12*68*4 floats = 102 KB; 17-stride swizzle
    // keeps reduce reads at 2-way banks. Reused as decoder scratch.
    __shared__ float red[8 * 12 * 68 * 4];
    __shared__ float cst[768];                 // c state [cell][jj][b], block-private
    __shared__ float sbias[48];
    __shared__ float sbias2[16];               // AR fused bias (cell0 rows)
    __shared__ unsigned long long hstage[192]; // h packing stage [cell][b] -> 4 halfs

    const int tid = threadIdx.x;
    const int bid = blockIdx.x;
    const int lane = tid & 63;
    const int wid = tid >> 6;
    const int laneA0 = (lane >> 4) * 512 + (lane & 15) * 8;

    if (tid < 48) sbias[tid] = bsum[bid * 48 + tid];
    if (tid >= 64 && tid < 80) sbias2[tid - 64] = bsum2[bid * 16 + (tid - 64)];
    for (int i = tid; i < 768; i += NTHR) cst[i] = 0.0f;

    // Load this wave's 25 weight fragments into registers, once.
    h8 wfr[25];
    {
        const _Float16* wp = wblob + (size_t)bid * WPB + (size_t)(wid * 25) * 512 + lane * 8;
#pragma unroll
        for (int s2 = 0; s2 < 25; ++s2) wfr[s2] = *(const h8*)(wp + s2 * 512);
    }
    __syncthreads();

    const int gnum = gnum_p[0];
    const int per = gnum + cnum_p[0];

    unsigned epA = 0;
    int tmod = 0;
    for (int t = 0; t < Tn; ++t) {
        const int flag = (tmod < gnum) ? 1 : 0;
        const bool fused = (!flag) && (t > 0); // t==0 AR: prev_out == 0, no x-term
        const int rb = t % 3, wb2 = (t + 1) % 3;
        const _Float16* hr = hT + (size_t)rb * HBUF;
        _Float16* hw = hT + (size_t)wb2 * HBUF;

        f4 acc[12]; // [cell][mt]
#pragma unroll
        for (int i = 0; i < 12; ++i) acc[i] = (f4){0.f, 0.f, 0.f, 0.f};

        // x phase (TF steps only): waves 0-4 cover K=160 (kt=wid), cell0.
        if (flag && wid < 5) {
            const _Float16* x0 = xT + (size_t)t * XTT + wid * 2048 + laneA0;
#pragma unroll
            for (int mt = 0; mt < 4; ++mt) {
                h8 a = *(const h8*)(x0 + mt * 128);
                acc[mt] = __builtin_amdgcn_mfma_f32_16x16x32_f16(a, wfr[20], acc[mt], 0, 0, 0);
            }
        }
        // h0: Whh1 -> cell0, Wih2 -> cell1 (shared A-frags, coherent loads)
        {
            const _Float16* s0 = hr + wid * 4 * 2048 + laneA0;
#pragma unroll
            for (int i2 = 0; i2 < 4; ++i2) {
#pragma unroll
                for (int mt = 0; mt < 4; ++mt) {
                    h8 a = cload16(s0 + i2 * 2048 + mt * 128);
                    acc[mt]     = __builtin_amdgcn_mfma_f32_16x16x32_f16(a, wfr[i2],     acc[mt],     0, 0, 0);
                    acc[4 + mt] = __builtin_amdgcn_mfma_f32_16x16x32_f16(a, wfr[4 + i2], acc[4 + mt], 0, 0, 0);
                }
            }
        }
        // h1: Whh2 -> cell1, Wih3 -> cell2
        {
            const _Float16* s1 = hr + SRCH + wid * 4 * 2048 + laneA0;
#pragma unroll
            for (int i2 = 0; i2 < 4; ++i2) {
#pragma unroll
                for (int mt = 0; mt < 4; ++mt) {
                    h8 a = cload16(s1 + i2 * 2048 + mt * 128);
                    acc[4 + mt] = __builtin_amdgcn_mfma_f32_16x16x32_f16(a, wfr[8 + i2],  acc[4 + mt], 0, 0, 0);
                    acc[8 + mt] = __builtin_amdgcn_mfma_f32_16x16x32_f16(a, wfr[12 + i2], acc[8 + mt], 0, 0, 0);
                }
            }
        }
        // h2: Whh3 -> cell2; on AR steps also W1d -> cell0 (same A-frags).
        {
            const _Float16* s2 = hr + 2 * SRCH + wid * 4 * 2048 + laneA0;
            if (fused) {
#pragma unroll
                for (int i2 = 0; i2 < 4; ++i2) {
#pragma unroll
                    for (int mt = 0; mt < 4; ++mt) {
                        h8 a = cload16(s2 + i2 * 2048 + mt * 128);
                        acc[8 + mt] = __builtin_amdgcn_mfma_f32_16x16x32_f16(a, wfr[16 + i2], acc[8 + mt], 0, 0, 0);
                        acc[mt]     = __builtin_amdgcn_mfma_f32_16x16x32_f16(a, wfr[21 + i2], acc[mt],     0, 0, 0);
                    }
                }
            } else {
#pragma unroll
                for (int i2 = 0; i2 < 4; ++i2) {
#pragma unroll
                    for (int mt = 0; mt < 4; ++mt) {
                        h8 a = cload16(s2 + i2 * 2048 + mt * 128);
                        acc[8 + mt] = __builtin_amdgcn_mfma_f32_16x16x32_f16(a, wfr[16 + i2], acc[8 + mt], 0, 0, 0);
                    }
                }
            }
        }

        // ---- 8-way K-reduce + gates + state update ----
        {
            float* wr = red + ((size_t)(wid * 12) * 68 + (lane >> 4) * 17 + (lane & 15)) * 4;
#pragma unroll
            for (int cc = 0; cc < 3; ++cc)
#pragma unroll
                for (int mt = 0; mt < 4; ++mt)
                    *(f4*)(wr + (cc * 4 + mt) * 68 * 4) = acc[cc * 4 + mt];
        }
        __syncthreads();
        const float bmul = fused ? 1.0f : 0.0f;
        for (int idx = tid; idx < 768; idx += NTHR) {
            const int cell = idx >> 8, jj = (idx >> 6) & 3, b = idx & 63;
            const int mt = b >> 4, mq = (b >> 2) & 3, rr = b & 3;
            float gv4[4];
#pragma unroll
            for (int gt = 0; gt < 4; ++gt) {
                const int n = gt * 4 + jj;
                float v = sbias[cell * 16 + n];
                if (cell == 0) v += bmul * sbias2[n];
#pragma unroll
                for (int w2 = 0; w2 < 8; ++w2)
                    v += red[(((w2 * 12 + cell * 4 + mt)) * 68 + mq * 17 + n) * 4 + rr];
                gv4[gt] = v;
            }
            const float cold = cst[(cell * 4 + jj) * 64 + b];
            const float cn = sigf(gv4[1]) * cold + sigf(gv4[0]) * tanhf(gv4[2]);
            cst[(cell * 4 + jj) * 64 + b] = cn;
            const float hn = sigf(gv4[3]) * tanhf(cn);
            ((_Float16*)hstage)[(cell * 64 + b) * 4 + jj] = (_Float16)hn;
        }
        __syncthreads();
        if (tid < 192) { // pack 4 halfs -> one coherent 8B store
            const int cell = tid >> 6, b = tid & 63;
            _Float16* dst = hw + cell * SRCH + (bid >> 1) * 512 + b * 8 + 4 * (bid & 1);
            cstore8(dst, hstage[tid]);
        }

        ++epA;
        gsyncA(bar, epA); // all h_new at coherence point

        // ---- decoder (off critical path): dout += h2_new @ Wd^T + bd ------
        // 264 (f, K-half) jobs over 256 blocks; blocks 0..7 take a second job.
        {
            const _Float16* h2 = hT + (size_t)wb2 * HBUF + 2 * SRCH;
            const int ss = tid >> 6, b = tid & 63;
            const int nj = (bid < 8) ? 2 : 1;
            for (int j2 = 0; j2 < nj; ++j2) {
                int f, half;
                if (j2 == 0) {
                    if (bid < Fn) { f = bid; half = 0; }
                    else          { f = bid - Fn; half = 1; }
                } else { f = bid + (NBLK - Fn); half = 1; }
                const float* wdr = Wd + (size_t)f * Hn;
                float p = 0.0f;
#pragma unroll
                for (int i = 0; i < 8; ++i) {
                    const int k8 = half * 64 + ss * 8 + i;
                    h8 hv = cload16(h2 + k8 * 512 + b * 8);
                    const float4 w0 = *(const float4*)(wdr + k8 * 8);
                    const float4 w1 = *(const float4*)(wdr + k8 * 8 + 4);
                    p = fmaf((float)hv[0], w0.x, p); p = fmaf((float)hv[1], w0.y, p);
                    p = fmaf((float)hv[2], w0.z, p); p = fmaf((float)hv[3], w0.w, p);
                    p = fmaf((float)hv[4], w1.x, p); p = fmaf((float)hv[5], w1.y, p);
                    p = fmaf((float)hv[6], w1.z, p); p = fmaf((float)hv[7], w1.w, p);
                }
                red[ss * 64 + b] = p;
                __syncthreads();
                if (tid < 64) {
                    float o = (half == 0) ? bd[f] : 0.0f;
#pragma unroll
                    for (int u = 0; u < 8; ++u) o += red[u * 64 + tid];
                    unsafeAtomicAdd(&dout[(size_t)tid * TF + (size_t)t * Fn + f], o);
                }
                __syncthreads(); // red reused
            }
        }
        tmod = (tmod + 1 >= per) ? 0 : (tmod + 1);
    }
}

// ---------------- host ------------------------------------------------------

extern "C" void kernel_launch(void* const* d_in, const int* in_sizes, int n_in,
                              void* d_out, int out_size, void* d_ws, size_t ws_size,
                              hipStream_t stream) {
    const float* xseq = (const float*)d_in[0];
    const float* Wih1 = (const float*)d_in[1];
    const float* Whh1 = (const float*)d_in[2];
    const float* bih1 = (const float*)d_in[3];
    const float* bhh1 = (const float*)d_in[4];
    const float* Wih2 = (const float*)d_in[5];
    const float* Whh2 = (const float*)d_in[6];
    const float* bih2 = (const float*)d_in[7];
    const float* bhh2 = (const float*)d_in[8];
    const float* Wih3 = (const float*)d_in[9];
    const float* Whh3 = (const float*)d_in[10];
    const float* bih3 = (const float*)d_in[11];
    const float* bhh3 = (const float*)d_in[12];
    const float* Wd = (const float*)d_in[13];
    const float* bd = (const float*)d_in[14];
    const int* cnum_p = (const int*)d_in[15];
    const int* gnum_p = (const int*)d_in[16];

    unsigned char* ws = (unsigned char*)d_ws;
    unsigned* bar = (unsigned*)ws;                       // 4096 B
    float* bsum = (float*)(ws + 4096);                   // NBLK*48 f32
    float* bsum2 = (float*)(ws + 53248);                 // NBLK*16 f32 (16K used)
    _Float16* xT = (_Float16*)(ws + 102400);             // 5,242,880 halfs
    _Float16* wblob = (_Float16*)(ws + 102400 + 10485760);           // 26,214,400 halfs
    _Float16* hT = (_Float16*)(ws + 102400 + 10485760 + 52428800);   // 589,824 halfs

    hipMemsetAsync(bar, 0, 4096, stream);
    hipMemsetAsync(d_out, 0, (size_t)out_size * sizeof(float), stream);
    hipLaunchKernelGGL(k_bsum, dim3((NBLK * 64 + 255) / 256), dim3(256), 0, stream,
                       bih1, bhh1, bih2, bhh2, bih3, bhh3, Wih1, bd, bsum, bsum2);
    hipLaunchKernelGGL(k_convx, dim3((Tn * XTT + 255) / 256), dim3(256), 0, stream,
                       xseq, xT);
    hipLaunchKernelGGL(k_convw, dim3((NBLK * WPB + 255) / 256), dim3(256), 0, stream,
                       Wih1, Whh1, Wih2, Whh2, Wih3, Whh3, Wd, wblob);
    hipLaunchKernelGGL(k_misc, dim3((HBUF + 255) / 256), dim3(256), 0, stream, hT);
    hipLaunchKernelGGL(lstm_mfma, dim3(NBLK), dim3(NTHR), 0, stream,
                       xT, wblob, hT, bsum, bsum2, Wd, bd, cnum_p, gnum_p,
                       (float*)d_out, bar);
}

// Round 7
// 7701.154 us; speedup vs baseline: 21.1969x; 1.1151x over previous
//
#include <hip/hip_runtime.h>
#include <cstdint>

// Persistent fp16-MFMA 3-layer autoregressive LSTM. B=64,T=512,F=132,H=1024.
// Round 7: per-XCD L2 staging. R6 was L3-coherence-BW-bound: 256 blocks x
// 384 KB/step of sc0+sc1 h loads = 98 MB/step at ~5.9 TB/s = the whole step.
// Now each XCD's blocks cooperatively stage the h image once (agent reads,
// 8x384KB/step at L3) into a per-XCD buffer with PLAIN write-back stores
// (dirty in own L2), and compute reads it with sc0-only buffer loads (L1
// bypass, L2 hit) -> h traffic served by the 8 L2s (~34.5 TB/s aggregate).
// XCD identity via s_getreg(HW_REG_XCC_ID) + dynamic registration (dispatch
// mapping undefined). Decoder for step t-1 runs inside the global-barrier
// window (arrive -> decode -> poll), reading the staged slot.

#define NBLK 256
#define NTHR 512
#define Bn 64
#define Tn 512
#define Fn 132
#define Hn 1024
#define TF (Tn * Fn)          // 67584
#define SRCH 65536            // halfs per h source (64*1024), layout [k8][b][8]
#define HBUF 196608           // halfs per h buffer (3 sources)
#define XTT 10240             // halfs per timestep of xT (20 k8 * 64 * 8)
#define WPB 102400            // halfs of weight blob per block (8 waves * 25 slots * 512)
#define STB 393216            // bytes per staged h image (3*64*1024*2)
#define STU 49152             // 8B units per staged image

typedef _Float16 h8 __attribute__((ext_vector_type(8)));
typedef float f4 __attribute__((ext_vector_type(4)));
typedef int v4i __attribute__((ext_vector_type(4)));
typedef unsigned long long ull;

// Raw buffer load, compiler-tracked vmcnt, aux=1 -> sc0 (L1 bypass, L2 hit).
__device__ v4i llvm_amdgcn_raw_buffer_load_v4i32(v4i srsrc, int voffset,
                                                 int soffset, int aux)
    __asm("llvm.amdgcn.raw.buffer.load.v4i32");

__device__ __forceinline__ v4i make_srd(const void* p) {
    union { struct { unsigned lo, hi, sz, cfg; } s; v4i v; } u;
    u.s.lo = (unsigned)(uintptr_t)p;
    u.s.hi = (unsigned)((uintptr_t)p >> 32); // stride=0
    u.s.sz = 0xFFFFFFFFu;                    // disable bounds check
    u.s.cfg = 0x00020000u;                   // raw dword access
    return u.v;
}

__device__ __forceinline__ h8 bload16(v4i rsrc, int voff) {
    union { v4i i; h8 h; } c;
    c.i = llvm_amdgcn_raw_buffer_load_v4i32(rsrc, voff, 0, 1 /*sc0*/);
    return c.h;
}

__device__ __forceinline__ float sigf(float x) { return 1.0f / (1.0f + expf(-x)); }

__device__ __forceinline__ ull cload8(const void* p) {
    return __hip_atomic_load((const ull*)p, __ATOMIC_RELAXED, __HIP_MEMORY_SCOPE_AGENT);
}
__device__ __forceinline__ void cstore8(void* p, ull v) {
    __hip_atomic_store((ull*)p, v, __ATOMIC_RELAXED, __HIP_MEMORY_SCOPE_AGENT);
}

// Global barrier pieces (2-level relaxed arrive, relaxed poll).
__device__ __forceinline__ void garrive(unsigned* bar, unsigned ep) {
    unsigned* cnt = bar + ((blockIdx.x >> 5) << 5);
    unsigned old = __hip_atomic_fetch_add(cnt, 1u, __ATOMIC_RELAXED,
                                          __HIP_MEMORY_SCOPE_AGENT);
    if (old == 32u * ep - 1u) {
        unsigned d = __hip_atomic_fetch_add(bar + 256, 1u, __ATOMIC_RELAXED,
                                            __HIP_MEMORY_SCOPE_AGENT);
        if (d == 8u * ep - 1u)
            __hip_atomic_store(bar + 288, ep, __ATOMIC_RELAXED,
                               __HIP_MEMORY_SCOPE_AGENT);
    }
}
__device__ __forceinline__ void gwait(unsigned* bar, unsigned ep) {
    while (__hip_atomic_load(bar + 288, __ATOMIC_RELAXED,
                             __HIP_MEMORY_SCOPE_AGENT) < ep)
        __builtin_amdgcn_s_sleep(1);
}
__device__ __forceinline__ void gsyncA(unsigned* bar, unsigned ep) {
    __syncthreads();
    if (threadIdx.x == 0) { garrive(bar, ep); gwait(bar, ep); }
    __syncthreads();
}

// ---------------- convert kernels (once per launch) -------------------------

__global__ void k_bsum(const float* bih1, const float* bhh1, const float* bih2,
                       const float* bhh2, const float* bih3, const float* bhh3,
                       const float* Wih1, const float* bd,
                       float* bsum, float* bsum2) {
    int i = blockIdx.x * 256 + threadIdx.x;
    if (i < NBLK * 48) {
        int bidw = i / 48, r = i % 48;
        int cell = r >> 4, n = r & 15;
        int row = (n >> 2) * Hn + bidw * 4 + (n & 3);
        const float* bi = cell == 0 ? bih1 : (cell == 1 ? bih2 : bih3);
        const float* bh = cell == 0 ? bhh1 : (cell == 1 ? bhh2 : bhh3);
        bsum[i] = bi[row] + bh[row];
    } else if (i < NBLK * 64) {
        int ii = i - NBLK * 48;
        int bidw = ii / 16, n = ii % 16;
        int row = (n >> 2) * Hn + bidw * 4 + (n & 3);
        float s = 0.0f;
        for (int f = 0; f < Fn; ++f) s += Wih1[(size_t)row * Fn + f] * bd[f];
        bsum2[bidw * 16 + n] = s;
    }
}

__global__ void k_convx(const float* xseq, _Float16* xT) {
    int i = blockIdx.x * 256 + threadIdx.x;
    if (i >= Tn * XTT) return;
    int t = i / XTT, r = i % XTT;
    int k8 = r >> 9, b = (r >> 3) & 63, e = r & 7;
    int f = k8 * 8 + e;
    float v = (f < Fn) ? xseq[((size_t)b * Tn + t) * Fn + f] : 0.0f;
    xT[i] = (_Float16)v;
}

// Weight blob: [block][wave][slot 0..24][frag 512 halfs].
// slot 0-3: Whh1 kt=w*4+s | 4-7: Wih2 | 8-11: Whh2 | 12-15: Wih3 | 16-19: Whh3
// slot 20: Wih1 kt=w (waves 0-4) | slot 21-24: W1d = Wih1@Wd.
__global__ void k_convw(const float* Wih1, const float* Whh1, const float* Wih2,
                        const float* Whh2, const float* Wih3, const float* Whh3,
                        const float* Wd, _Float16* wblob) {
    int i = blockIdx.x * 256 + threadIdx.x;
    if (i >= NBLK * WPB) return;
    int bidw = i / WPB, r = i % WPB;
    int slot = r >> 9, e = r & 511;
    int w = slot / 25, s = slot - w * 25;
    int l = e >> 3, j = e & 7;
    int kq = l >> 4, n = l & 15;
    int row = (n >> 2) * Hn + bidw * 4 + (n & 3);
    float v = 0.0f;
    if (s >= 21) {
        int kt = w * 4 + (s - 21);
        int k = kt * 32 + kq * 8 + j;
        float acc = 0.0f;
        for (int f = 0; f < Fn; ++f)
            acc += Wih1[(size_t)row * Fn + f] * Wd[(size_t)f * Hn + k];
        v = acc;
    } else {
        const float* M;
        int K, kt;
        if (s < 4)       { M = Whh1; K = Hn; kt = w * 4 + s; }
        else if (s < 8)  { M = Wih2; K = Hn; kt = w * 4 + s - 4; }
        else if (s < 12) { M = Whh2; K = Hn; kt = w * 4 + s - 8; }
        else if (s < 16) { M = Wih3; K = Hn; kt = w * 4 + s - 12; }
        else if (s < 20) { M = Whh3; K = Hn; kt = w * 4 + s - 16; }
        else             { M = Wih1; K = Fn; kt = w; }
        int k = kt * 32 + kq * 8 + j;
        if (!(s == 20 && w >= 5) && k < K) v = M[(size_t)row * K + k];
    }
    wblob[i] = (_Float16)v;
}

__global__ void k_misc(_Float16* hT) {
    int i = blockIdx.x * 256 + threadIdx.x;
    if (i < HBUF) hT[i] = (_Float16)0.0f;
}

// ---------------- persistent kernel ----------------------------------------

__global__ __launch_bounds__(NTHR, 2) void lstm_mfma(
    const _Float16* __restrict__ xT, const _Float16* __restrict__ wblob,
    _Float16* __restrict__ hT, unsigned char* __restrict__ xstage,
    const float* __restrict__ bsum, const float* __restrict__ bsum2,
    const float* __restrict__ Wd, const float* __restrict__ bd,
    const int* __restrict__ cnum_p, const int* __restrict__ gnum_p,
    float* __restrict__ dout, unsigned* __restrict__ bar) {
    __shared__ float red[8 * 12 * 68 * 4];     // 102 KB reduce scratch
    __shared__ float cst[768];                 // c state [cell][jj][b]
    __shared__ float sbias[48];
    __shared__ float sbias2[16];
    __shared__ unsigned long long hstage[192];
    __shared__ int sxi[3];                     // xcd, rank, Nx

    const int tid = threadIdx.x;
    const int bid = blockIdx.x;
    const int lane = tid & 63;
    const int wid = tid >> 6;
    const int laneAB = (lane >> 4) * 1024 + (lane & 15) * 16; // A-frag byte off
    const int laneA0 = (lane >> 4) * 512 + (lane & 15) * 8;   // same, halfs
    const int widB = wid * 16384;

    if (tid < 48) sbias[tid] = bsum[bid * 48 + tid];
    if (tid >= 64 && tid < 80) sbias2[tid - 64] = bsum2[bid * 16 + (tid - 64)];
    for (int i = tid; i < 768; i += NTHR) cst[i] = 0.0f;

    // Weight fragments -> registers, once.
    h8 wfr[25];
    {
        const _Float16* wp = wblob + (size_t)bid * WPB + (size_t)(wid * 25) * 512 + lane * 8;
#pragma unroll
        for (int s2 = 0; s2 < 25; ++s2) wfr[s2] = *(const h8*)(wp + s2 * 512);
    }

    // ---- XCD registration (dispatch->XCD mapping is undefined; discover) ----
    if (tid == 0) {
        unsigned x;
        asm volatile("s_getreg_b32 %0, hwreg(HW_REG_XCC_ID)" : "=s"(x));
        x &= 7u;
        unsigned r = __hip_atomic_fetch_add(bar + 384 + x * 16, 1u,
                                            __ATOMIC_RELAXED, __HIP_MEMORY_SCOPE_AGENT);
        sxi[0] = (int)x; sxi[1] = (int)r;
    }
    gsyncA(bar, 1); // all registered
    if (tid == 0)
        sxi[2] = (int)__hip_atomic_load(bar + 384 + sxi[0] * 16, __ATOMIC_RELAXED,
                                        __HIP_MEMORY_SCOPE_AGENT);
    __syncthreads();
    const int xcd = sxi[0], xrank = sxi[1], xN = sxi[2];
    unsigned* xb = bar + 640 + xcd * 16;
    unsigned char* xsb = xstage + (size_t)xcd * 2 * STB;

    const int gnum = gnum_p[0];
    const int per = gnum + cnum_p[0];

    // Decoder for output row tt, reading staged h2 via rsrc (all threads).
    auto decoder = [&](v4i rsrc, int tt) {
        const int ss = tid >> 6, b = tid & 63;
        const int nj = (bid < 8) ? 2 : 1;
        for (int j2 = 0; j2 < nj; ++j2) {
            int f, half;
            if (j2 == 0) {
                if (bid < Fn) { f = bid; half = 0; }
                else          { f = bid - Fn; half = 1; }
            } else { f = bid + (NBLK - Fn); half = 1; }
            const float* wdr = Wd + (size_t)f * Hn;
            float p = 0.0f;
#pragma unroll
            for (int i = 0; i < 8; ++i) {
                const int k8 = half * 64 + ss * 8 + i;
                h8 hv = bload16(rsrc, 262144 + k8 * 1024 + b * 16);
                const float4 w0 = *(const float4*)(wdr + k8 * 8);
                const float4 w1 = *(const float4*)(wdr + k8 * 8 + 4);
                p = fmaf((float)hv[0], w0.x, p); p = fmaf((float)hv[1], w0.y, p);
                p = fmaf((float)hv[2], w0.z, p); p = fmaf((float)hv[3], w0.w, p);
                p = fmaf((float)hv[4], w1.x, p); p = fmaf((float)hv[5], w1.y, p);
                p = fmaf((float)hv[6], w1.z, p); p = fmaf((float)hv[7], w1.w, p);
            }
            red[ss * 64 + b] = p;
            __syncthreads();
            if (tid < 64) {
                float o = (half == 0) ? bd[f] : 0.0f;
#pragma unroll
                for (int u = 0; u < 8; ++u) o += red[u * 64 + tid];
                unsafeAtomicAdd(&dout[(size_t)tid * TF + (size_t)tt * Fn + f], o);
            }
            __syncthreads();
        }
    };

    // Stage the h image for buffer rbuf into slot: agent reads, plain writes.
    auto stage = [&](int rbuf, int slot) {
        const ull* src = (const ull*)(hT + (size_t)rbuf * HBUF);
        ull* dst = (ull*)(xsb + (size_t)slot * STB);
        for (int s2 = xrank; s2 < 32; s2 += xN) {
            const int u = s2 * 1536 + tid;
#pragma unroll
            for (int q = 0; q < 3; ++q)
                dst[u + q * 512] = cload8(src + u + q * 512);
        }
        __syncthreads(); // drain staging stores (vmcnt) before arrival
    };
    auto xsync = [&](unsigned target) {
        if (tid == 0) {
            __hip_atomic_fetch_add(xb, 1u, __ATOMIC_RELAXED, __HIP_MEMORY_SCOPE_AGENT);
            while (__hip_atomic_load(xb, __ATOMIC_RELAXED, __HIP_MEMORY_SCOPE_AGENT) < target)
                __builtin_amdgcn_s_sleep(1);
        }
        __syncthreads();
    };

    int tmod = 0;
    for (int t = 0; t < Tn; ++t) {
        const int flag = (tmod < gnum) ? 1 : 0;
        const bool fused = (!flag) && (t > 0);
        const int rb = t % 3, wb2 = (t + 1) % 3;
        _Float16* hw = hT + (size_t)wb2 * HBUF;

        // ---- stage h(t-1) image into this XCD's L2, then XCD barrier ----
        stage(rb, t & 1);
        xsync((unsigned)(xN * (t + 1)));
        const v4i rsrc = make_srd(xsb + (size_t)(t & 1) * STB);

        f4 acc[12]; // [cell][mt]
#pragma unroll
        for (int i = 0; i < 12; ++i) acc[i] = (f4){0.f, 0.f, 0.f, 0.f};

        // x phase (TF steps): waves 0-4 cover K=160 (kt=wid), cell0.
        if (flag && wid < 5) {
            const _Float16* x0 = xT + (size_t)t * XTT + wid * 2048 + laneA0;
#pragma unroll
            for (int mt = 0; mt < 4; ++mt) {
                h8 a = *(const h8*)(x0 + mt * 128);
                acc[mt] = __builtin_amdgcn_mfma_f32_16x16x32_f16(a, wfr[20], acc[mt], 0, 0, 0);
            }
        }
        // h0: Whh1 -> cell0, Wih2 -> cell1 (staged, sc0 L2 hits)
#pragma unroll
        for (int i2 = 0; i2 < 4; ++i2) {
#pragma unroll
            for (int mt = 0; mt < 4; ++mt) {
                h8 a = bload16(rsrc, widB + i2 * 4096 + mt * 256 + laneAB);
                acc[mt]     = __builtin_amdgcn_mfma_f32_16x16x32_f16(a, wfr[i2],     acc[mt],     0, 0, 0);
                acc[4 + mt] = __builtin_amdgcn_mfma_f32_16x16x32_f16(a, wfr[4 + i2], acc[4 + mt], 0, 0, 0);
            }
        }
        // h1: Whh2 -> cell1, Wih3 -> cell2
#pragma unroll
        for (int i2 = 0; i2 < 4; ++i2) {
#pragma unroll
            for (int mt = 0; mt < 4; ++mt) {
                h8 a = bload16(rsrc, 131072 + widB + i2 * 4096 + mt * 256 + laneAB);
                acc[4 + mt] = __builtin_amdgcn_mfma_f32_16x16x32_f16(a, wfr[8 + i2],  acc[4 + mt], 0, 0, 0);
                acc[8 + mt] = __builtin_amdgcn_mfma_f32_16x16x32_f16(a, wfr[12 + i2], acc[8 + mt], 0, 0, 0);
            }
        }
        // h2: Whh3 -> cell2; AR steps also W1d -> cell0 (same A-frags)
        if (fused) {
#pragma unroll
            for (int i2 = 0; i2 < 4; ++i2) {
#pragma unroll
                for (int mt = 0; mt < 4; ++mt) {
                    h8 a = bload16(rsrc, 262144 + widB + i2 * 4096 + mt * 256 + laneAB);
                    acc[8 + mt] = __builtin_amdgcn_mfma_f32_16x16x32_f16(a, wfr[16 + i2], acc[8 + mt], 0, 0, 0);
                    acc[mt]     = __builtin_amdgcn_mfma_f32_16x16x32_f16(a, wfr[21 + i2], acc[mt],     0, 0, 0);
                }
            }
        } else {
#pragma unroll
            for (int i2 = 0; i2 < 4; ++i2) {
#pragma unroll
                for (int mt = 0; mt < 4; ++mt) {
                    h8 a = bload16(rsrc, 262144 + widB + i2 * 4096 + mt * 256 + laneAB);
                    acc[8 + mt] = __builtin_amdgcn_mfma_f32_16x16x32_f16(a, wfr[16 + i2], acc[8 + mt], 0, 0, 0);
                }
            }
        }

        // ---- 8-way K-reduce + gates + state update ----
        {
            float* wr = red + ((size_t)(wid * 12) * 68 + (lane >> 4) * 17 + (lane & 15)) * 4;
#pragma unroll
            for (int cc = 0; cc < 3; ++cc)
#pragma unroll
                for (int mt = 0; mt < 4; ++mt)
                    *(f4*)(wr + (cc * 4 + mt) * 68 * 4) = acc[cc * 4 + mt];
        }
        __syncthreads();
        const float bmul = fused ? 1.0f : 0.0f;
        for (int idx = tid; idx < 768; idx += NTHR) {
            const int cell = idx >> 8, jj = (idx >> 6) & 3, b = idx & 63;
            const int mt = b >> 4, mq = (b >> 2) & 3, rr = b & 3;
            float gv4[4];
#pragma unroll
            for (int gt = 0; gt < 4; ++gt) {
                const int n = gt * 4 + jj;
                float v = sbias[cell * 16 + n];
                if (cell == 0) v += bmul * sbias2[n];
#pragma unroll
                for (int w2 = 0; w2 < 8; ++w2)
                    v += red[(((w2 * 12 + cell * 4 + mt)) * 68 + mq * 17 + n) * 4 + rr];
                gv4[gt] = v;
            }
            const float cold = cst[(cell * 4 + jj) * 64 + b];
            const float cn = sigf(gv4[1]) * cold + sigf(gv4[0]) * tanhf(gv4[2]);
            cst[(cell * 4 + jj) * 64 + b] = cn;
            const float hn = sigf(gv4[3]) * tanhf(cn);
            ((_Float16*)hstage)[(cell * 64 + b) * 4 + jj] = (_Float16)hn;
        }
        __syncthreads();
        if (tid < 192) { // pack 4 halfs -> one coherent 8B store to hT
            const int cell = tid >> 6, b = tid & 63;
            _Float16* dst = hw + cell * SRCH + (bid >> 1) * 512 + b * 8 + 4 * (bid & 1);
            cstore8(dst, hstage[tid]);
        }

        // ---- global barrier with decoder hidden in the wait window ----
        __syncthreads(); // drain h stores before arrival
        if (tid == 0) garrive(bar, (unsigned)(t + 2));
        if (t > 0) decoder(rsrc, t - 1); // staged slot t&1 holds h(t-1) image
        __syncthreads();
        if (tid == 0) gwait(bar, (unsigned)(t + 2));
        __syncthreads();

        tmod = (tmod + 1 >= per) ? 0 : (tmod + 1);
    }

    // Tail: stage the final h image and emit dout[Tn-1].
    stage(Tn % 3, Tn & 1);
    xsync((unsigned)(xN * (Tn + 1)));
    decoder(make_srd(xsb + (size_t)(Tn & 1) * STB), Tn - 1);
}

// ---------------- host ------------------------------------------------------

extern "C" void kernel_launch(void* const* d_in, const int* in_sizes, int n_in,
                              void* d_out, int out_size, void* d_ws, size_t ws_size,
                              hipStream_t stream) {
    const float* xseq = (const float*)d_in[0];
    const float* Wih1 = (const float*)d_in[1];
    const float* Whh1 = (const float*)d_in[2];
    const float* bih1 = (const float*)d_in[3];
    const float* bhh1 = (const float*)d_in[4];
    const float* Wih2 = (const float*)d_in[5];
    const float* Whh2 = (const float*)d_in[6];
    const float* bih2 = (const float*)d_in[7];
    const float* bhh2 = (const float*)d_in[8];
    const float* Wih3 = (const float*)d_in[9];
    const float* Whh3 = (const float*)d_in[10];
    const float* bih3 = (const float*)d_in[11];
    const float* bhh3 = (const float*)d_in[12];
    const float* Wd = (const float*)d_in[13];
    const float* bd = (const float*)d_in[14];
    const int* cnum_p = (const int*)d_in[15];
    const int* gnum_p = (const int*)d_in[16];

    unsigned char* ws = (unsigned char*)d_ws;
    unsigned* bar = (unsigned*)ws;                       // 4096 B (gbar/reg/xbar)
    float* bsum = (float*)(ws + 4096);                   // NBLK*48 f32
    float* bsum2 = (float*)(ws + 53248);                 // NBLK*16 f32
    _Float16* xT = (_Float16*)(ws + 102400);             // 10,485,760 B
    _Float16* wblob = (_Float16*)(ws + 102400 + 10485760);           // 52,428,800 B
    _Float16* hT = (_Float16*)(ws + 102400 + 10485760 + 52428800);   // 1,179,648 B
    unsigned char* xstage = ws + 102400 + 10485760 + 52428800 + 1179648; // 6,291,456 B

    hipMemsetAsync(bar, 0, 4096, stream);
    hipMemsetAsync(d_out, 0, (size_t)out_size * sizeof(float), stream);
    hipLaunchKernelGGL(k_bsum, dim3((NBLK * 64 + 255) / 256), dim3(256), 0, stream,
                       bih1, bhh1, bih2, bhh2, bih3, bhh3, Wih1, bd, bsum, bsum2);
    hipLaunchKernelGGL(k_convx, dim3((Tn * XTT + 255) / 256), dim3(256), 0, stream,
                       xseq, xT);
    hipLaunchKernelGGL(k_convw, dim3((NBLK * WPB + 255) / 256), dim3(256), 0, stream,
                       Wih1, Whh1, Wih2, Whh2, Wih3, Whh3, Wd, wblob);
    hipLaunchKernelGGL(k_misc, dim3((HBUF + 255) / 256), dim3(256), 0, stream, hT);
    hipLaunchKernelGGL(lstm_mfma, dim3(NBLK), dim3(NTHR), 0, stream,
                       xT, wblob, hT, xstage, bsum, bsum2, Wd, bd, cnum_p, gnum_p,
                       (float*)d_out, bar);
}